// Round 3
// baseline (530.552 us; speedup 1.0000x reference)
//
#include <hip/hip_runtime.h>
#include <hip/hip_bf16.h>

#define BB 4
#define SEQ 2048
#define NH 4
#define D 64
#define NPAIR (BB*NH)
#define HOUT 8

// ws layout (floats): tot[NPAIR][3][4096] (SU,SV,KV) then stats[NPAIR][128] (colmax64, colsum64)
#define TOT_ELEMS (NPAIR * 3 * 4096)

__global__ __launch_bounds__(256) void zero_tot(float* __restrict__ t) {
    int i = blockIdx.x * 256 + threadIdx.x;
    if (i < TOT_ELEMS) t[i] = 0.0f;
}

// ---------------- V column stats: colmax / colsum over L per (b,h,x) ----------------
__global__ __launch_bounds__(1024) void vt_stats(const float* __restrict__ V, float* __restrict__ stats) {
    int p = blockIdx.x;
    int b = p / NH, h = p % NH;
    int x = threadIdx.x & 63;
    int c = threadIdx.x >> 6;                 // 0..15
    __shared__ float red[16][64];
    __shared__ float colmax[64];
    const size_t base = (size_t)(b * SEQ * NH + h) * D + x;
    const int stride = NH * D;

    float m = -INFINITY;
    for (int l = c; l < SEQ; l += 16) m = fmaxf(m, V[base + (size_t)l * stride]);
    red[c][x] = m;
    __syncthreads();
    if (c == 0) {
        float mm = red[0][x];
#pragma unroll
        for (int i = 1; i < 16; i++) mm = fmaxf(mm, red[i][x]);
        colmax[x] = mm;
        stats[p * 128 + x] = mm;
    }
    __syncthreads();
    float mm = colmax[x];
    float s = 0.0f;
    for (int l = c; l < SEQ; l += 16) s += __expf(V[base + (size_t)l * stride] - mm);
    __syncthreads();                          // pass-1 reads of red done
    red[c][x] = s;
    __syncthreads();
    if (c == 0) {
        float ss = 0.0f;
#pragma unroll
        for (int i = 0; i < 16; i++) ss += red[i][x];
        stats[p * 128 + 64 + x] = ss;
    }
}

// ---------------- Gram SU = Uh^T Uh (recompute row-softmax in-kernel) ----------------
__global__ __launch_bounds__(256) void gram_u(const float* __restrict__ U, float* __restrict__ tot) {
    int chunk = blockIdx.x;                   // 0..3 (512 rows each)
    int p = blockIdx.y;
    int b = p / NH, h = p % NH;
    int tid = threadIdx.x;
    int tx = tid & 15, ty = tid >> 4;
    int row8 = tid >> 3;                      // 0..31
    int c8 = (tid & 7) * 8;
    __shared__ __align__(16) float Ut[32][68];
    float su[4][4] = {};

    for (int sub = 0; sub < 16; ++sub) {
        int lb = chunk * 512 + sub * 32;
        __syncthreads();
        {
            const float4* src = (const float4*)(U + ((size_t)((b * SEQ + lb + row8) * NH + h)) * D + c8);
            float4 q0 = src[0], q1 = src[1];
            float v[8] = {q0.x, q0.y, q0.z, q0.w, q1.x, q1.y, q1.z, q1.w};
            float mx = v[0];
#pragma unroll
            for (int k = 1; k < 8; k++) mx = fmaxf(mx, v[k]);
            mx = fmaxf(mx, __shfl_xor(mx, 1));
            mx = fmaxf(mx, __shfl_xor(mx, 2));
            mx = fmaxf(mx, __shfl_xor(mx, 4));
            float sm = 0.0f;
#pragma unroll
            for (int k = 0; k < 8; k++) { v[k] = __expf(v[k] - mx); sm += v[k]; }
            sm += __shfl_xor(sm, 1);
            sm += __shfl_xor(sm, 2);
            sm += __shfl_xor(sm, 4);
            float inv = 1.0f / sm;
#pragma unroll
            for (int k = 0; k < 8; k++) Ut[row8][c8 + k] = v[k] * inv;
        }
        __syncthreads();
#pragma unroll 4
        for (int rr = 0; rr < 32; ++rr) {
            float4 t1 = *(const float4*)&Ut[rr][ty * 4];
            float4 t2 = *(const float4*)&Ut[rr][tx * 4];
            float ux[4] = {t1.x, t1.y, t1.z, t1.w};
            float ue[4] = {t2.x, t2.y, t2.z, t2.w};
#pragma unroll
            for (int a = 0; a < 4; a++)
#pragma unroll
                for (int e = 0; e < 4; e++) su[a][e] = fmaf(ux[a], ue[e], su[a][e]);
        }
    }
    float* dst = tot + (size_t)p * 3 * 4096;
#pragma unroll
    for (int a = 0; a < 4; a++)
#pragma unroll
        for (int e = 0; e < 4; e++)
            atomicAdd(&dst[(ty * 4 + a) * 64 + tx * 4 + e], su[a][e]);
}

// ---------------- Gram SV = W^T W, KV = W^T vals (W from stats on the fly) ----------------
__global__ __launch_bounds__(256) void gram_v(const float* __restrict__ V, const float* __restrict__ vals,
                                              const float* __restrict__ stats, float* __restrict__ tot) {
    int chunk = blockIdx.x;
    int p = blockIdx.y;
    int b = p / NH, h = p % NH;
    int tid = threadIdx.x;
    int tx = tid & 15, ty = tid >> 4;
    int row8 = tid >> 3;
    int c8 = (tid & 7) * 8;
    __shared__ __align__(16) float Wt[32][68];
    __shared__ __align__(16) float Vv[32][68];
    __shared__ float cm[64], ci[64];
    if (tid < 64) cm[tid] = stats[p * 128 + tid];
    else if (tid < 128) ci[tid - 64] = 1.0f / stats[p * 128 + tid];
    float sv[4][4] = {}, kv[4][4] = {};

    for (int sub = 0; sub < 16; ++sub) {
        int lb = chunk * 512 + sub * 32;
        __syncthreads();
        {
            size_t base = ((size_t)((b * SEQ + lb + row8) * NH + h)) * D + c8;
            const float4* vp = (const float4*)(V + base);
            const float4* ap = (const float4*)(vals + base);
            float4 v0 = vp[0], v1 = vp[1], a0 = ap[0], a1 = ap[1];
            float wv[8] = {v0.x, v0.y, v0.z, v0.w, v1.x, v1.y, v1.z, v1.w};
            float av[8] = {a0.x, a0.y, a0.z, a0.w, a1.x, a1.y, a1.z, a1.w};
#pragma unroll
            for (int k = 0; k < 8; k++) {
                Wt[row8][c8 + k] = __expf(wv[k] - cm[c8 + k]) * ci[c8 + k];
                Vv[row8][c8 + k] = av[k];
            }
        }
        __syncthreads();
#pragma unroll 4
        for (int rr = 0; rr < 32; ++rr) {
            float4 t1 = *(const float4*)&Wt[rr][ty * 4];
            float4 t2 = *(const float4*)&Wt[rr][tx * 4];
            float4 t3 = *(const float4*)&Vv[rr][tx * 4];
            float wx[4] = {t1.x, t1.y, t1.z, t1.w};
            float we[4] = {t2.x, t2.y, t2.z, t2.w};
            float ve[4] = {t3.x, t3.y, t3.z, t3.w};
#pragma unroll
            for (int a = 0; a < 4; a++)
#pragma unroll
                for (int e = 0; e < 4; e++) {
                    sv[a][e] = fmaf(wx[a], we[e], sv[a][e]);
                    kv[a][e] = fmaf(wx[a], ve[e], kv[a][e]);
                }
        }
    }
    float* dst = tot + (size_t)p * 3 * 4096;
#pragma unroll
    for (int a = 0; a < 4; a++)
#pragma unroll
        for (int e = 0; e < 4; e++) {
            int off = (ty * 4 + a) * 64 + tx * 4 + e;
            atomicAdd(&dst[4096 + off], sv[a][e]);
            atomicAdd(&dst[8192 + off], kv[a][e]);
        }
}

// ---------------- AGF output: out = (Uh*gf) @ KV, Uh/gf recomputed in-kernel ----------------
__global__ __launch_bounds__(256) void agf_out(const float* __restrict__ U, const float* __restrict__ Sg,
                                               const float* __restrict__ gam, const float* __restrict__ tot,
                                               float* __restrict__ out) {
    int lt = blockIdx.x;                      // 0..31
    int p = blockIdx.y;
    int b = p / NH, h = p % NH;
    int tid = threadIdx.x;
    __shared__ __align__(16) float kvs[64][68];
    __shared__ __align__(16) float ugs[64][68];
    const float* kvsrc = tot + (size_t)(p * 3 + 2) * 4096;
    for (int idx = tid; idx < 4096; idx += 256) kvs[idx >> 6][idx & 63] = kvsrc[idx];
    {
        int row = tid >> 2;                   // 0..63
        int c16 = (tid & 3) * 16;
        size_t ibase = ((size_t)((b * SEQ + lt * 64 + row) * NH + h)) * D + c16;
        const float4* up = (const float4*)(U + ibase);
        float uv[16];
#pragma unroll
        for (int k4 = 0; k4 < 4; k4++) {
            float4 t = up[k4];
            uv[k4 * 4 + 0] = t.x; uv[k4 * 4 + 1] = t.y; uv[k4 * 4 + 2] = t.z; uv[k4 * 4 + 3] = t.w;
        }
        float mx = uv[0];
#pragma unroll
        for (int k = 1; k < 16; k++) mx = fmaxf(mx, uv[k]);
        mx = fmaxf(mx, __shfl_xor(mx, 1));
        mx = fmaxf(mx, __shfl_xor(mx, 2));
        float sm = 0.0f;
#pragma unroll
        for (int k = 0; k < 16; k++) { uv[k] = __expf(uv[k] - mx); sm += uv[k]; }
        sm += __shfl_xor(sm, 1);
        sm += __shfl_xor(sm, 2);
        float inv = 1.0f / sm;
        const float4* sp = (const float4*)(Sg + ibase);
        float sg[16];
#pragma unroll
        for (int k4 = 0; k4 < 4; k4++) {
            float4 t = sp[k4];
            sg[k4 * 4 + 0] = t.x; sg[k4 * 4 + 1] = t.y; sg[k4 * 4 + 2] = t.z; sg[k4 * 4 + 3] = t.w;
        }
        float g0 = gam[0], g1 = gam[1], g2 = gam[2], g3 = gam[3];
#pragma unroll
        for (int k = 0; k < 16; k++) {
            float sig = 1.0f / (1.0f + __expf(-sg[k]));
            float x1 = 2.0f * sig;
            float x2 = 1.875f * sig * x1 - 0.75f;
            float x3 = 1.8666666666666667f * sig * x2 - 0.8f * x1;
            float gf = g0 + g1 * x1 + g2 * x2 + g3 * x3;
            ugs[row][c16 + k] = uv[k] * inv * gf;
        }
    }
    __syncthreads();
    int tx = tid & 15, ty = tid >> 4;
    float acc[4][4] = {};
#pragma unroll 8
    for (int x = 0; x < 64; x++) {
        float4 kt = *(const float4*)&kvs[x][tx * 4];
        float kb[4] = {kt.x, kt.y, kt.z, kt.w};
#pragma unroll
        for (int a = 0; a < 4; a++) {
            float ua = ugs[ty * 4 + a][x];
#pragma unroll
            for (int e = 0; e < 4; e++) acc[a][e] = fmaf(ua, kb[e], acc[a][e]);
        }
    }
#pragma unroll
    for (int a = 0; a < 4; a++)
#pragma unroll
        for (int e = 0; e < 4; e++)
            out[((size_t)(b * SEQ + lt * 64 + ty * 4 + a) * HOUT + h) * D + tx * 4 + e] = acc[a][e];
}

// ---------------- ortho loss ----------------
__global__ __launch_bounds__(256) void ortho_k(const float* __restrict__ tot, float* __restrict__ out) {
    int b = blockIdx.x;
    float s = 0.0f;
    for (int idx = threadIdx.x; idx < NH * 2 * 4096; idx += 256) {
        int h = idx >> 13;
        int m = (idx >> 12) & 1;
        int i = idx & 4095;
        float v = tot[(size_t)((b * NH + h) * 3 + m) * 4096 + i];
        float dg = ((i >> 6) == (i & 63)) ? 1.0f : 0.0f;
        s += fabsf(v - dg);
    }
#pragma unroll
    for (int o = 32; o > 0; o >>= 1) s += __shfl_xor(s, o);
    __shared__ float r4[4];
    if ((threadIdx.x & 63) == 0) r4[threadIdx.x >> 6] = s;
    __syncthreads();
    if (threadIdx.x == 0) {
        float t = r4[0] + r4[1] + r4[2] + r4[3];
        out[(size_t)BB * SEQ * HOUT * D + b] = t * (1.0f / 16384.0f);
    }
}

// ---------------- flash attention for softmax heads (LDS 52.2 KB) ----------------
__global__ __launch_bounds__(256) void flash(const float* __restrict__ Q, const float* __restrict__ K,
                                             const float* __restrict__ V, float* __restrict__ out) {
    int qt = blockIdx.x;                      // 0..31
    int p = blockIdx.y;                       // 0..15
    int b = p >> 2, h = p & 3;
    __shared__ __align__(16) float QsT[64][68];   // [x][i], pre-scaled
    __shared__ __align__(16) float KPT[64][68];   // K^T [x][j] during S; P^T [j][i] during PV
    __shared__ __align__(16) float Vs[64][68];    // [j][e]
    const int tid = threadIdx.x;
    int tx = tid & 15, ty = tid >> 4;

    {   // load Q tile transposed + scaled
        int i = tid >> 2;
        int x0 = (tid & 3) << 4;
        const float4* src = (const float4*)(Q + ((size_t)(b * SEQ + qt * 64 + i) * NH + h) * D + x0);
#pragma unroll
        for (int k4 = 0; k4 < 4; k4++) {
            float4 t = src[k4];
            QsT[x0 + k4 * 4 + 0][i] = t.x * 0.125f;
            QsT[x0 + k4 * 4 + 1][i] = t.y * 0.125f;
            QsT[x0 + k4 * 4 + 2][i] = t.z * 0.125f;
            QsT[x0 + k4 * 4 + 3][i] = t.w * 0.125f;
        }
    }

    float m[4], lsum[4], o[4][4];
#pragma unroll
    for (int a = 0; a < 4; a++) {
        m[a] = -INFINITY; lsum[a] = 0.0f;
#pragma unroll
        for (int e = 0; e < 4; e++) o[a][e] = 0.0f;
    }

    for (int kt = 0; kt < SEQ / 64; ++kt) {
        __syncthreads();                      // prev iteration's PV reads done
        {
            int j = tid >> 2;
            int x0 = (tid & 3) << 4;
            const float4* ks = (const float4*)(K + ((size_t)(b * SEQ + kt * 64 + j) * NH + h) * D + x0);
            const float4* vs = (const float4*)(V + ((size_t)(b * SEQ + kt * 64 + j) * NH + h) * D + x0);
#pragma unroll
            for (int k4 = 0; k4 < 4; k4++) {
                float4 tk = ks[k4];
                float4 tv = vs[k4];
                KPT[x0 + k4 * 4 + 0][j] = tk.x;
                KPT[x0 + k4 * 4 + 1][j] = tk.y;
                KPT[x0 + k4 * 4 + 2][j] = tk.z;
                KPT[x0 + k4 * 4 + 3][j] = tk.w;
                Vs[j][x0 + k4 * 4 + 0] = tv.x;
                Vs[j][x0 + k4 * 4 + 1] = tv.y;
                Vs[j][x0 + k4 * 4 + 2] = tv.z;
                Vs[j][x0 + k4 * 4 + 3] = tv.w;
            }
        }
        __syncthreads();

        float s[4][4] = {};
#pragma unroll 8
        for (int x = 0; x < 64; x++) {
            float4 q4 = *(const float4*)&QsT[x][ty * 4];
            float4 k4 = *(const float4*)&KPT[x][tx * 4];
            float qa[4] = {q4.x, q4.y, q4.z, q4.w};
            float kb[4] = {k4.x, k4.y, k4.z, k4.w};
#pragma unroll
            for (int a = 0; a < 4; a++)
#pragma unroll
                for (int e = 0; e < 4; e++) s[a][e] = fmaf(qa[a], kb[e], s[a][e]);
        }
        __syncthreads();                      // all S-reads of KPT done before P overwrite

#pragma unroll
        for (int a = 0; a < 4; a++) {
            float rm = fmaxf(fmaxf(s[a][0], s[a][1]), fmaxf(s[a][2], s[a][3]));
            rm = fmaxf(rm, __shfl_xor(rm, 1));
            rm = fmaxf(rm, __shfl_xor(rm, 2));
            rm = fmaxf(rm, __shfl_xor(rm, 4));
            rm = fmaxf(rm, __shfl_xor(rm, 8));
            float mn = fmaxf(m[a], rm);
            float alpha = __expf(m[a] - mn);
            float pv[4];
            float rs = 0.0f;
#pragma unroll
            for (int e = 0; e < 4; e++) { pv[e] = __expf(s[a][e] - mn); rs += pv[e]; }
            rs += __shfl_xor(rs, 1);
            rs += __shfl_xor(rs, 2);
            rs += __shfl_xor(rs, 4);
            rs += __shfl_xor(rs, 8);
            lsum[a] = lsum[a] * alpha + rs;
            m[a] = mn;
#pragma unroll
            for (int e = 0; e < 4; e++) o[a][e] *= alpha;
#pragma unroll
            for (int e = 0; e < 4; e++) KPT[tx * 4 + e][ty * 4 + a] = pv[e];   // P^T [j][i]
        }
        __syncthreads();

#pragma unroll 8
        for (int j = 0; j < 64; j++) {
            float4 p4 = *(const float4*)&KPT[j][ty * 4];
            float4 v4 = *(const float4*)&Vs[j][tx * 4];
            float pa[4] = {p4.x, p4.y, p4.z, p4.w};
            float vb[4] = {v4.x, v4.y, v4.z, v4.w};
#pragma unroll
            for (int a = 0; a < 4; a++)
#pragma unroll
                for (int e = 0; e < 4; e++) o[a][e] = fmaf(pa[a], vb[e], o[a][e]);
        }
    }

#pragma unroll
    for (int a = 0; a < 4; a++) {
        float inv = 1.0f / lsum[a];
#pragma unroll
        for (int e = 0; e < 4; e++)
            out[((size_t)(b * SEQ + qt * 64 + ty * 4 + a) * HOUT + 4 + h) * D + tx * 4 + e] =
                o[a][e] * inv;
    }
}

extern "C" void kernel_launch(void* const* d_in, const int* in_sizes, int n_in,
                              void* d_out, int out_size, void* d_ws, size_t ws_size,
                              hipStream_t stream) {
    (void)in_sizes; (void)n_in; (void)out_size; (void)ws_size;
    const float* U    = (const float*)d_in[0];
    const float* Sg   = (const float*)d_in[1];
    const float* V    = (const float*)d_in[2];
    const float* vals = (const float*)d_in[3];
    const float* Qs   = (const float*)d_in[4];
    const float* Ks   = (const float*)d_in[5];
    const float* Vv   = (const float*)d_in[6];
    const float* gam  = (const float*)d_in[7];
    float* out = (float*)d_out;

    float* tot   = (float*)d_ws;                       // NPAIR*3*4096 floats
    float* stats = tot + TOT_ELEMS;                    // NPAIR*128 floats  (total < 0.8 MB)

    zero_tot<<<(TOT_ELEMS + 255) / 256, 256, 0, stream>>>(tot);
    vt_stats<<<NPAIR, 1024, 0, stream>>>(V, stats);
    gram_u<<<dim3(4, NPAIR), 256, 0, stream>>>(U, tot);
    gram_v<<<dim3(4, NPAIR), 256, 0, stream>>>(V, vals, stats, tot);
    agf_out<<<dim3(SEQ / 64, NPAIR), 256, 0, stream>>>(U, Sg, gam, tot, out);
    ortho_k<<<BB, 256, 0, stream>>>(tot, out);
    flash<<<dim3(SEQ / 64, NPAIR), 256, 0, stream>>>(Qs, Ks, Vv, out);
}

// Round 4
// 330.013 us; speedup vs baseline: 1.6077x; 1.6077x over previous
//
#include <hip/hip_runtime.h>
#include <hip/hip_bf16.h>

#define BB 4
#define SEQ 2048
#define NH 4
#define D 64
#define NPAIR (BB*NH)
#define HOUT 8
#define LOSS_BASE ((size_t)BB * SEQ * HOUT * D)

// ws layout (floats): tot[NPAIR][3][4096] | stats[NPAIR][128] | vpart[NPAIR][8][128]
#define TOT_ELEMS (NPAIR * 3 * 4096)

typedef __attribute__((ext_vector_type(8))) short bf16x8;
typedef __attribute__((ext_vector_type(4))) float f32x4;
typedef __attribute__((ext_vector_type(8))) unsigned short us8;
typedef __attribute__((ext_vector_type(4))) unsigned short us4;

__device__ __forceinline__ unsigned short f2bf(float x) {
    union { float f; unsigned u; } v; v.f = x;
    unsigned r = v.u + 0x7fffu + ((v.u >> 16) & 1u);
    return (unsigned short)(r >> 16);
}
__device__ __forceinline__ float bf2f(unsigned short u) {
    union { unsigned u; float f; } v; v.u = ((unsigned)u) << 16; return v.f;
}

__global__ __launch_bounds__(256) void zero_tot(float* __restrict__ t, float* __restrict__ out) {
    int i = blockIdx.x * 256 + threadIdx.x;
    if (i < TOT_ELEMS) t[i] = 0.0f;
    if (i < BB) out[LOSS_BASE + i] = 0.0f;
}

// ---------------- V column stats phase 1: per-(p,seg) colmax + colsumexp ----------------
__global__ __launch_bounds__(256) void vt_part(const float* __restrict__ V, float* __restrict__ part) {
    int p = blockIdx.x, seg = blockIdx.y;
    int b = p / NH, h = p % NH;
    int x = threadIdx.x & 63;
    int c = threadIdx.x >> 6;                 // 0..3
    __shared__ float red[4][64];
    __shared__ float cmax[64];
    const size_t base = ((size_t)(b * SEQ + seg * 256) * NH + h) * D + x;
    const int stride = NH * D;

    float m = -INFINITY;
    for (int l = c; l < 256; l += 4) m = fmaxf(m, V[base + (size_t)l * stride]);
    red[c][x] = m;
    __syncthreads();
    if (c == 0) {
        float mm = fmaxf(fmaxf(red[0][x], red[1][x]), fmaxf(red[2][x], red[3][x]));
        cmax[x] = mm;
    }
    __syncthreads();
    float mm = cmax[x];
    float s = 0.0f;
    for (int l = c; l < 256; l += 4) s += __expf(V[base + (size_t)l * stride] - mm);
    __syncthreads();
    red[c][x] = s;
    __syncthreads();
    if (c == 0) {
        float ss = red[0][x] + red[1][x] + red[2][x] + red[3][x];
        part[(size_t)(p * 8 + seg) * 128 + x] = mm;
        part[(size_t)(p * 8 + seg) * 128 + 64 + x] = ss;
    }
}

// ---------------- V column stats phase 2: merge 8 segments ----------------
__global__ __launch_bounds__(64) void vt_merge(const float* __restrict__ part, float* __restrict__ stats) {
    int p = blockIdx.x, x = threadIdx.x;
    float M = -INFINITY;
#pragma unroll
    for (int s = 0; s < 8; s++) M = fmaxf(M, part[(size_t)(p * 8 + s) * 128 + x]);
    float S = 0.0f;
#pragma unroll
    for (int s = 0; s < 8; s++)
        S += part[(size_t)(p * 8 + s) * 128 + 64 + x] * __expf(part[(size_t)(p * 8 + s) * 128 + x] - M);
    stats[p * 128 + x] = M;
    stats[p * 128 + 64 + x] = S;
}

// ---------------- Gram SU = Uh^T Uh ----------------
__global__ __launch_bounds__(256) void gram_u(const float* __restrict__ U, float* __restrict__ tot) {
    int chunk = blockIdx.x;                   // 0..15 (128 rows each)
    int p = blockIdx.y;
    int b = p / NH, h = p % NH;
    int tid = threadIdx.x;
    int tx = tid & 15, ty = tid >> 4;
    int row8 = tid >> 3;                      // 0..31
    int c8 = (tid & 7) * 8;
    __shared__ __align__(16) float Ut[32][68];
    float su[4][4] = {};

    for (int sub = 0; sub < 4; ++sub) {
        int lb = chunk * 128 + sub * 32;
        __syncthreads();
        {
            const float4* src = (const float4*)(U + ((size_t)((b * SEQ + lb + row8) * NH + h)) * D + c8);
            float4 q0 = src[0], q1 = src[1];
            float v[8] = {q0.x, q0.y, q0.z, q0.w, q1.x, q1.y, q1.z, q1.w};
            float mx = v[0];
#pragma unroll
            for (int k = 1; k < 8; k++) mx = fmaxf(mx, v[k]);
            mx = fmaxf(mx, __shfl_xor(mx, 1));
            mx = fmaxf(mx, __shfl_xor(mx, 2));
            mx = fmaxf(mx, __shfl_xor(mx, 4));
            float sm = 0.0f;
#pragma unroll
            for (int k = 0; k < 8; k++) { v[k] = __expf(v[k] - mx); sm += v[k]; }
            sm += __shfl_xor(sm, 1);
            sm += __shfl_xor(sm, 2);
            sm += __shfl_xor(sm, 4);
            float inv = 1.0f / sm;
#pragma unroll
            for (int k = 0; k < 8; k++) Ut[row8][c8 + k] = v[k] * inv;
        }
        __syncthreads();
#pragma unroll 4
        for (int rr = 0; rr < 32; ++rr) {
            float4 t1 = *(const float4*)&Ut[rr][ty * 4];
            float4 t2 = *(const float4*)&Ut[rr][tx * 4];
            float ux[4] = {t1.x, t1.y, t1.z, t1.w};
            float ue[4] = {t2.x, t2.y, t2.z, t2.w};
#pragma unroll
            for (int a = 0; a < 4; a++)
#pragma unroll
                for (int e = 0; e < 4; e++) su[a][e] = fmaf(ux[a], ue[e], su[a][e]);
        }
    }
    float* dst = tot + (size_t)p * 3 * 4096;
#pragma unroll
    for (int a = 0; a < 4; a++)
#pragma unroll
        for (int e = 0; e < 4; e++)
            atomicAdd(&dst[(ty * 4 + a) * 64 + tx * 4 + e], su[a][e]);
}

// ---------------- Gram SV = W^T W, KV = W^T vals ----------------
__global__ __launch_bounds__(256) void gram_v(const float* __restrict__ V, const float* __restrict__ vals,
                                              const float* __restrict__ stats, float* __restrict__ tot) {
    int chunk = blockIdx.x;                   // 0..15
    int p = blockIdx.y;
    int b = p / NH, h = p % NH;
    int tid = threadIdx.x;
    int tx = tid & 15, ty = tid >> 4;
    int row8 = tid >> 3;
    int c8 = (tid & 7) * 8;
    __shared__ __align__(16) float Wt[32][68];
    __shared__ __align__(16) float Vv[32][68];
    __shared__ float cm[64], ci[64];
    if (tid < 64) cm[tid] = stats[p * 128 + tid];
    else if (tid < 128) ci[tid - 64] = 1.0f / stats[p * 128 + tid];
    float sv[4][4] = {}, kv[4][4] = {};

    for (int sub = 0; sub < 4; ++sub) {
        int lb = chunk * 128 + sub * 32;
        __syncthreads();
        {
            size_t base = ((size_t)((b * SEQ + lb + row8) * NH + h)) * D + c8;
            const float4* vp = (const float4*)(V + base);
            const float4* ap = (const float4*)(vals + base);
            float4 v0 = vp[0], v1 = vp[1], a0 = ap[0], a1 = ap[1];
            float wv[8] = {v0.x, v0.y, v0.z, v0.w, v1.x, v1.y, v1.z, v1.w};
            float av[8] = {a0.x, a0.y, a0.z, a0.w, a1.x, a1.y, a1.z, a1.w};
#pragma unroll
            for (int k = 0; k < 8; k++) {
                Wt[row8][c8 + k] = __expf(wv[k] - cm[c8 + k]) * ci[c8 + k];
                Vv[row8][c8 + k] = av[k];
            }
        }
        __syncthreads();
#pragma unroll 4
        for (int rr = 0; rr < 32; ++rr) {
            float4 t1 = *(const float4*)&Wt[rr][ty * 4];
            float4 t2 = *(const float4*)&Wt[rr][tx * 4];
            float4 t3 = *(const float4*)&Vv[rr][tx * 4];
            float wx[4] = {t1.x, t1.y, t1.z, t1.w};
            float we[4] = {t2.x, t2.y, t2.z, t2.w};
            float ve[4] = {t3.x, t3.y, t3.z, t3.w};
#pragma unroll
            for (int a = 0; a < 4; a++)
#pragma unroll
                for (int e = 0; e < 4; e++) {
                    sv[a][e] = fmaf(wx[a], we[e], sv[a][e]);
                    kv[a][e] = fmaf(wx[a], ve[e], kv[a][e]);
                }
        }
    }
    float* dst = tot + (size_t)p * 3 * 4096;
#pragma unroll
    for (int a = 0; a < 4; a++)
#pragma unroll
        for (int e = 0; e < 4; e++) {
            int off = (ty * 4 + a) * 64 + tx * 4 + e;
            atomicAdd(&dst[4096 + off], sv[a][e]);
            atomicAdd(&dst[8192 + off], kv[a][e]);
        }
}

// ---------------- AGF output: out = (Uh*gf) @ KV ----------------
__global__ __launch_bounds__(256) void agf_out(const float* __restrict__ U, const float* __restrict__ Sg,
                                               const float* __restrict__ gam, const float* __restrict__ tot,
                                               float* __restrict__ out) {
    int lt = blockIdx.x;                      // 0..31
    int p = blockIdx.y;
    int b = p / NH, h = p % NH;
    int tid = threadIdx.x;
    __shared__ __align__(16) float kvs[64][68];
    __shared__ __align__(16) float ugs[64][68];
    const float* kvsrc = tot + (size_t)(p * 3 + 2) * 4096;
    for (int idx = tid; idx < 4096; idx += 256) kvs[idx >> 6][idx & 63] = kvsrc[idx];
    {
        int row = tid >> 2;                   // 0..63
        int c16 = (tid & 3) * 16;
        size_t ibase = ((size_t)((b * SEQ + lt * 64 + row) * NH + h)) * D + c16;
        const float4* up = (const float4*)(U + ibase);
        float uv[16];
#pragma unroll
        for (int k4 = 0; k4 < 4; k4++) {
            float4 t = up[k4];
            uv[k4 * 4 + 0] = t.x; uv[k4 * 4 + 1] = t.y; uv[k4 * 4 + 2] = t.z; uv[k4 * 4 + 3] = t.w;
        }
        float mx = uv[0];
#pragma unroll
        for (int k = 1; k < 16; k++) mx = fmaxf(mx, uv[k]);
        mx = fmaxf(mx, __shfl_xor(mx, 1));
        mx = fmaxf(mx, __shfl_xor(mx, 2));
        float sm = 0.0f;
#pragma unroll
        for (int k = 0; k < 16; k++) { uv[k] = __expf(uv[k] - mx); sm += uv[k]; }
        sm += __shfl_xor(sm, 1);
        sm += __shfl_xor(sm, 2);
        float inv = 1.0f / sm;
        const float4* sp = (const float4*)(Sg + ibase);
        float sg[16];
#pragma unroll
        for (int k4 = 0; k4 < 4; k4++) {
            float4 t = sp[k4];
            sg[k4 * 4 + 0] = t.x; sg[k4 * 4 + 1] = t.y; sg[k4 * 4 + 2] = t.z; sg[k4 * 4 + 3] = t.w;
        }
        float g0 = gam[0], g1 = gam[1], g2 = gam[2], g3 = gam[3];
#pragma unroll
        for (int k = 0; k < 16; k++) {
            float sig = 1.0f / (1.0f + __expf(-sg[k]));
            float x1 = 2.0f * sig;
            float x2 = 1.875f * sig * x1 - 0.75f;
            float x3 = 1.8666666666666667f * sig * x2 - 0.8f * x1;
            float gf = g0 + g1 * x1 + g2 * x2 + g3 * x3;
            ugs[row][c16 + k] = uv[k] * inv * gf;
        }
    }
    __syncthreads();
    int tx = tid & 15, ty = tid >> 4;
    float acc[4][4] = {};
#pragma unroll 8
    for (int x = 0; x < 64; x++) {
        float4 kt = *(const float4*)&kvs[x][tx * 4];
        float kb[4] = {kt.x, kt.y, kt.z, kt.w};
#pragma unroll
        for (int a = 0; a < 4; a++) {
            float ua = ugs[ty * 4 + a][x];
#pragma unroll
            for (int e = 0; e < 4; e++) acc[a][e] = fmaf(ua, kb[e], acc[a][e]);
        }
    }
#pragma unroll
    for (int a = 0; a < 4; a++)
#pragma unroll
        for (int e = 0; e < 4; e++)
            out[((size_t)(b * SEQ + lt * 64 + ty * 4 + a) * HOUT + h) * D + tx * 4 + e] = acc[a][e];
}

// ---------------- ortho loss: per-(b,h) partial, atomicAdd into out ----------------
__global__ __launch_bounds__(256) void ortho_p(const float* __restrict__ tot, float* __restrict__ out) {
    int p = blockIdx.x;
    int b = p / NH;
    float s = 0.0f;
    for (int idx = threadIdx.x; idx < 2 * 4096; idx += 256) {
        int m = idx >> 12;
        int i = idx & 4095;
        float v = tot[((size_t)p * 3 + m) * 4096 + i];
        float dg = ((i >> 6) == (i & 63)) ? 1.0f : 0.0f;
        s += fabsf(v - dg);
    }
#pragma unroll
    for (int o = 32; o > 0; o >>= 1) s += __shfl_xor(s, o);
    __shared__ float r4[4];
    if ((threadIdx.x & 63) == 0) r4[threadIdx.x >> 6] = s;
    __syncthreads();
    if (threadIdx.x == 0) {
        float t = r4[0] + r4[1] + r4[2] + r4[3];
        atomicAdd(&out[LOSS_BASE + b], t * (1.0f / 16384.0f));
    }
}

// ---------------- MFMA flash attention (bf16 hi/lo 3-pass, fp32 accumulate) ----------------
#define LSTR 72   // ushort row stride (+8 pad -> 2-way bank aliasing only, free)

__global__ __launch_bounds__(256) void flash_mfma(const float* __restrict__ Q, const float* __restrict__ K,
                                                  const float* __restrict__ V, float* __restrict__ out) {
    int qt = blockIdx.x;                      // 0..31
    int p = blockIdx.y;                       // 0..15
    int b = p >> 2, h = p & 3;
    __shared__ __align__(16) unsigned short Khi[64 * LSTR], Klo[64 * LSTR];
    __shared__ __align__(16) unsigned short Vhi[64 * LSTR], Vlo[64 * LSTR];   // transposed: [d][key]
    __shared__ __align__(16) unsigned short Phi[4][16 * LSTR], Plo[4][16 * LSTR];
    const int tid = threadIdx.x;
    const int w = tid >> 6, lane = tid & 63;
    const int lm = lane & 15, quad = lane >> 4;

    // ---- Q A-frags, hi/lo, scale 1/8 folded in. A[m=lane&15][k=quad*8+j] ----
    bf16x8 qhi[2], qlo[2];
    {
        int row = qt * 64 + w * 16 + lm;
        const float* qp = Q + ((size_t)(b * SEQ + row) * NH + h) * D + quad * 8;
#pragma unroll
        for (int ks = 0; ks < 2; ks++) {
            float4 a0 = *(const float4*)(qp + ks * 32);
            float4 a1 = *(const float4*)(qp + ks * 32 + 4);
            float qq[8] = {a0.x, a0.y, a0.z, a0.w, a1.x, a1.y, a1.z, a1.w};
#pragma unroll
            for (int j = 0; j < 8; j++) {
                float xs = qq[j] * 0.125f;
                unsigned short hi = f2bf(xs);
                qhi[ks][j] = (short)hi;
                qlo[ks][j] = (short)f2bf(xs - bf2f(hi));
            }
        }
    }

    float mrun[4], lrun[4];
    f32x4 o[4];
#pragma unroll
    for (int r = 0; r < 4; r++) { mrun[r] = -INFINITY; lrun[r] = 0.0f; }
#pragma unroll
    for (int t = 0; t < 4; t++) o[t] = (f32x4){0.f, 0.f, 0.f, 0.f};

    for (int kt = 0; kt < SEQ / 64; ++kt) {
        __syncthreads();                      // previous iteration's K/V reads complete
        {   // stage K [key][d] hi/lo
            int j = tid >> 2;
            int c0 = (tid & 3) * 16;
            const float* kp = K + ((size_t)(b * SEQ + kt * 64 + j) * NH + h) * D + c0;
            float kk[16];
#pragma unroll
            for (int k4 = 0; k4 < 4; k4++) {
                float4 t = *(const float4*)(kp + k4 * 4);
                kk[k4 * 4] = t.x; kk[k4 * 4 + 1] = t.y; kk[k4 * 4 + 2] = t.z; kk[k4 * 4 + 3] = t.w;
            }
            us8 h0, h1, l0, l1;
#pragma unroll
            for (int i = 0; i < 8; i++) {
                unsigned short hi = f2bf(kk[i]);
                h0[i] = hi; l0[i] = f2bf(kk[i] - bf2f(hi));
            }
#pragma unroll
            for (int i = 0; i < 8; i++) {
                unsigned short hi = f2bf(kk[8 + i]);
                h1[i] = hi; l1[i] = f2bf(kk[8 + i] - bf2f(hi));
            }
            *(us8*)&Khi[j * LSTR + c0] = h0;
            *(us8*)&Khi[j * LSTR + c0 + 8] = h1;
            *(us8*)&Klo[j * LSTR + c0] = l0;
            *(us8*)&Klo[j * LSTR + c0 + 8] = l1;
        }
        {   // stage V transposed -> [d][key], via 4x4 register transpose
            int r0 = (tid & 15) * 4;          // key base
            int c0 = (tid >> 4) * 4;          // d base
            float vv[4][4];                   // [key i][d c]
#pragma unroll
            for (int i = 0; i < 4; i++) {
                float4 t = *(const float4*)(V + ((size_t)(b * SEQ + kt * 64 + r0 + i) * NH + h) * D + c0);
                vv[i][0] = t.x; vv[i][1] = t.y; vv[i][2] = t.z; vv[i][3] = t.w;
            }
#pragma unroll
            for (int c = 0; c < 4; c++) {
                us4 hv, lv;
#pragma unroll
                for (int i = 0; i < 4; i++) {
                    unsigned short hi = f2bf(vv[i][c]);
                    hv[i] = hi; lv[i] = f2bf(vv[i][c] - bf2f(hi));
                }
                *(us4*)&Vhi[(c0 + c) * LSTR + r0] = hv;
                *(us4*)&Vlo[(c0 + c) * LSTR + r0] = lv;
            }
        }
        __syncthreads();

        // ---- S = Q K^T : 4 key-tiles x 2 k-steps x 3 split passes ----
        f32x4 s[4];
#pragma unroll
        for (int t = 0; t < 4; t++) s[t] = (f32x4){0.f, 0.f, 0.f, 0.f};
#pragma unroll
        for (int t = 0; t < 4; t++) {
#pragma unroll
            for (int ks = 0; ks < 2; ks++) {
                int off = (t * 16 + lm) * LSTR + ks * 32 + quad * 8;
                bf16x8 kh = *(const bf16x8*)&Khi[off];
                bf16x8 kl = *(const bf16x8*)&Klo[off];
                s[t] = __builtin_amdgcn_mfma_f32_16x16x32_bf16(qhi[ks], kh, s[t], 0, 0, 0);
                s[t] = __builtin_amdgcn_mfma_f32_16x16x32_bf16(qhi[ks], kl, s[t], 0, 0, 0);
                s[t] = __builtin_amdgcn_mfma_f32_16x16x32_bf16(qlo[ks], kh, s[t], 0, 0, 0);
            }
        }

        // ---- online softmax in C-layout (row = quad*4+r, col = t*16 + lane&15) ----
        float pfrag[4][4];
#pragma unroll
        for (int r = 0; r < 4; r++) {
            float rm = fmaxf(fmaxf(s[0][r], s[1][r]), fmaxf(s[2][r], s[3][r]));
            rm = fmaxf(rm, __shfl_xor(rm, 1));
            rm = fmaxf(rm, __shfl_xor(rm, 2));
            rm = fmaxf(rm, __shfl_xor(rm, 4));
            rm = fmaxf(rm, __shfl_xor(rm, 8));
            float mn = fmaxf(mrun[r], rm);
            float alpha = __expf(mrun[r] - mn);
            mrun[r] = mn;
            float rs = 0.0f;
#pragma unroll
            for (int t = 0; t < 4; t++) { pfrag[t][r] = __expf(s[t][r] - mn); rs += pfrag[t][r]; }
            rs += __shfl_xor(rs, 1);
            rs += __shfl_xor(rs, 2);
            rs += __shfl_xor(rs, 4);
            rs += __shfl_xor(rs, 8);
            lrun[r] = lrun[r] * alpha + rs;
#pragma unroll
            for (int t = 0; t < 4; t++) o[t][r] *= alpha;
        }
        // write P (hi/lo) to this wave's LDS region: [Qrow 0..15][key 0..63]
#pragma unroll
        for (int t = 0; t < 4; t++)
#pragma unroll
            for (int r = 0; r < 4; r++) {
                unsigned short hi = f2bf(pfrag[t][r]);
                int off = (quad * 4 + r) * LSTR + t * 16 + lm;
                Phi[w][off] = hi;
                Plo[w][off] = f2bf(pfrag[t][r] - bf2f(hi));
            }
        // same-wave write->read ordering via lgkmcnt; no barrier needed (per-wave region)

        // ---- O += P V : A = P frag, B = V^T-stored frag ----
        bf16x8 ph[2], pl[2];
#pragma unroll
        for (int ks = 0; ks < 2; ks++) {
            int off = lm * LSTR + ks * 32 + quad * 8;
            ph[ks] = *(const bf16x8*)&Phi[w][off];
            pl[ks] = *(const bf16x8*)&Plo[w][off];
        }
#pragma unroll
        for (int dt = 0; dt < 4; dt++) {
#pragma unroll
            for (int ks = 0; ks < 2; ks++) {
                int off = (dt * 16 + lm) * LSTR + ks * 32 + quad * 8;
                bf16x8 vh = *(const bf16x8*)&Vhi[off];
                bf16x8 vl = *(const bf16x8*)&Vlo[off];
                o[dt] = __builtin_amdgcn_mfma_f32_16x16x32_bf16(ph[ks], vh, o[dt], 0, 0, 0);
                o[dt] = __builtin_amdgcn_mfma_f32_16x16x32_bf16(ph[ks], vl, o[dt], 0, 0, 0);
                o[dt] = __builtin_amdgcn_mfma_f32_16x16x32_bf16(pl[ks], vh, o[dt], 0, 0, 0);
            }
        }
    }

    // ---- epilogue: normalize + store (C-layout rows) ----
#pragma unroll
    for (int r = 0; r < 4; r++) {
        float inv = 1.0f / lrun[r];
        int row = qt * 64 + w * 16 + quad * 4 + r;
        float* op = out + ((size_t)(b * SEQ + row) * HOUT + 4 + h) * D + lm;
#pragma unroll
        for (int dt = 0; dt < 4; dt++) op[dt * 16] = o[dt][r] * inv;
    }
}

extern "C" void kernel_launch(void* const* d_in, const int* in_sizes, int n_in,
                              void* d_out, int out_size, void* d_ws, size_t ws_size,
                              hipStream_t stream) {
    (void)in_sizes; (void)n_in; (void)out_size; (void)ws_size;
    const float* U    = (const float*)d_in[0];
    const float* Sg   = (const float*)d_in[1];
    const float* V    = (const float*)d_in[2];
    const float* vals = (const float*)d_in[3];
    const float* Qs   = (const float*)d_in[4];
    const float* Ks   = (const float*)d_in[5];
    const float* Vv   = (const float*)d_in[6];
    const float* gam  = (const float*)d_in[7];
    float* out = (float*)d_out;

    float* tot   = (float*)d_ws;                       // NPAIR*3*4096
    float* stats = tot + TOT_ELEMS;                    // NPAIR*128
    float* vpart = stats + NPAIR * 128;                // NPAIR*8*128

    zero_tot<<<(TOT_ELEMS + 255) / 256, 256, 0, stream>>>(tot, out);
    vt_part<<<dim3(NPAIR, 8), 256, 0, stream>>>(V, vpart);
    vt_merge<<<NPAIR, 64, 0, stream>>>(vpart, stats);
    gram_u<<<dim3(16, NPAIR), 256, 0, stream>>>(U, tot);
    gram_v<<<dim3(16, NPAIR), 256, 0, stream>>>(V, vals, stats, tot);
    agf_out<<<dim3(SEQ / 64, NPAIR), 256, 0, stream>>>(U, Sg, gam, tot, out);
    ortho_p<<<NPAIR, 256, 0, stream>>>(tot, out);
    flash_mfma<<<dim3(SEQ / 64, NPAIR), 256, 0, stream>>>(Qs, Ks, Vv, out);
}

// Round 5
// 294.639 us; speedup vs baseline: 1.8007x; 1.1201x over previous
//
#include <hip/hip_runtime.h>
#include <hip/hip_bf16.h>

#define BB 4
#define SEQ 2048
#define NH 4
#define D 64
#define NPAIR (BB*NH)
#define HOUT 8
#define LOSS_BASE ((size_t)BB * SEQ * HOUT * D)

// ws layout (floats): tot[NPAIR][3][4096] | stats[NPAIR][128] | vpart[NPAIR][8][128]
// then (ushort): Khi[NPAIR][SEQ][64] | Klo[NPAIR][SEQ][64]
#define TOT_ELEMS (NPAIR * 3 * 4096)
#define WS_F32_HEAD (TOT_ELEMS + NPAIR * 128 + NPAIR * 8 * 128)   // 215040 floats

typedef __attribute__((ext_vector_type(8))) short bf16x8;
typedef __attribute__((ext_vector_type(4))) float f32x4;
typedef __attribute__((ext_vector_type(8))) unsigned short us8;
typedef __attribute__((ext_vector_type(4))) unsigned short us4;

__device__ __forceinline__ unsigned short f2bf(float x) {
    union { float f; unsigned u; } v; v.f = x;
    unsigned r = v.u + 0x7fffu + ((v.u >> 16) & 1u);
    return (unsigned short)(r >> 16);
}
__device__ __forceinline__ float bf2f(unsigned short u) {
    union { unsigned u; float f; } v; v.u = ((unsigned)u) << 16; return v.f;
}

// ---------------- prep: K -> bf16 hi/lo (repacked [p][l][d]) + zero tot + zero loss ----------------
// grid: [0,2048) K conversion, [2048, 2816) zero tot
__global__ __launch_bounds__(256) void prep(const float* __restrict__ K, float* __restrict__ tot,
                                            unsigned short* __restrict__ Khi, unsigned short* __restrict__ Klo,
                                            float* __restrict__ out) {
    int blk = blockIdx.x;
    int tid = threadIdx.x;
    if (blk < 2048) {
        int i = (blk * 256 + tid) * 4;        // over [p][l][d] = [16][2048][64]
        int p = i >> 17;
        int rem = i & 131071;
        int l = rem >> 6, d = rem & 63;
        int b = p >> 2, h = p & 3;
        float4 v = *(const float4*)(K + (((size_t)(b * SEQ + l) * NH + h) << 6) + d);
        float vv[4] = {v.x, v.y, v.z, v.w};
        us4 hi, lo;
#pragma unroll
        for (int k = 0; k < 4; k++) {
            unsigned short h16 = f2bf(vv[k]);
            hi[k] = h16;
            lo[k] = f2bf(vv[k] - bf2f(h16));
        }
        *(us4*)(Khi + i) = hi;
        *(us4*)(Klo + i) = lo;
    } else {
        int i = (blk - 2048) * 256 + tid;
        if (i < TOT_ELEMS) tot[i] = 0.0f;
        if (blk == 2048 && tid < BB) out[LOSS_BASE + tid] = 0.0f;
    }
}

// ---------------- V column stats phase 1 ----------------
__global__ __launch_bounds__(256) void vt_part(const float* __restrict__ V, float* __restrict__ part) {
    int p = blockIdx.x, seg = blockIdx.y;
    int b = p / NH, h = p % NH;
    int x = threadIdx.x & 63;
    int c = threadIdx.x >> 6;                 // 0..3
    __shared__ float red[4][64];
    __shared__ float cmax[64];
    const size_t base = ((size_t)(b * SEQ + seg * 256) * NH + h) * D + x;
    const int stride = NH * D;

    float m = -INFINITY;
    for (int l = c; l < 256; l += 4) m = fmaxf(m, V[base + (size_t)l * stride]);
    red[c][x] = m;
    __syncthreads();
    if (c == 0) {
        float mm = fmaxf(fmaxf(red[0][x], red[1][x]), fmaxf(red[2][x], red[3][x]));
        cmax[x] = mm;
    }
    __syncthreads();
    float mm = cmax[x];
    float s = 0.0f;
    for (int l = c; l < 256; l += 4) s += __expf(V[base + (size_t)l * stride] - mm);
    __syncthreads();
    red[c][x] = s;
    __syncthreads();
    if (c == 0) {
        float ss = red[0][x] + red[1][x] + red[2][x] + red[3][x];
        part[(size_t)(p * 8 + seg) * 128 + x] = mm;
        part[(size_t)(p * 8 + seg) * 128 + 64 + x] = ss;
    }
}

// ---------------- V column stats phase 2 ----------------
__global__ __launch_bounds__(64) void vt_merge(const float* __restrict__ part, float* __restrict__ stats) {
    int p = blockIdx.x, x = threadIdx.x;
    float M = -INFINITY;
#pragma unroll
    for (int s = 0; s < 8; s++) M = fmaxf(M, part[(size_t)(p * 8 + s) * 128 + x]);
    float S = 0.0f;
#pragma unroll
    for (int s = 0; s < 8; s++)
        S += part[(size_t)(p * 8 + s) * 128 + 64 + x] * __expf(part[(size_t)(p * 8 + s) * 128 + x] - M);
    stats[p * 128 + x] = M;
    stats[p * 128 + 64 + x] = S;
}

// ---------------- fused grams: z=0 -> SU = Uh^T Uh ; z=1 -> SV/KV ----------------
__global__ __launch_bounds__(256) void gram_uv(const float* __restrict__ U, const float* __restrict__ V,
                                               const float* __restrict__ vals, const float* __restrict__ stats,
                                               float* __restrict__ tot) {
    int chunk = blockIdx.x;                   // 0..15 (128 rows each)
    int p = blockIdx.y;
    int b = p / NH, h = p % NH;
    int tid = threadIdx.x;
    int tx = tid & 15, ty = tid >> 4;
    int row8 = tid >> 3;                      // 0..31
    int c8 = (tid & 7) * 8;

    if (blockIdx.z == 0) {
        __shared__ __align__(16) float Ut[32][68];
        float su[4][4] = {};
        for (int sub = 0; sub < 4; ++sub) {
            int lb = chunk * 128 + sub * 32;
            __syncthreads();
            {
                const float4* src = (const float4*)(U + ((size_t)((b * SEQ + lb + row8) * NH + h)) * D + c8);
                float4 q0 = src[0], q1 = src[1];
                float v[8] = {q0.x, q0.y, q0.z, q0.w, q1.x, q1.y, q1.z, q1.w};
                float mx = v[0];
#pragma unroll
                for (int k = 1; k < 8; k++) mx = fmaxf(mx, v[k]);
                mx = fmaxf(mx, __shfl_xor(mx, 1));
                mx = fmaxf(mx, __shfl_xor(mx, 2));
                mx = fmaxf(mx, __shfl_xor(mx, 4));
                float sm = 0.0f;
#pragma unroll
                for (int k = 0; k < 8; k++) { v[k] = __expf(v[k] - mx); sm += v[k]; }
                sm += __shfl_xor(sm, 1);
                sm += __shfl_xor(sm, 2);
                sm += __shfl_xor(sm, 4);
                float inv = 1.0f / sm;
#pragma unroll
                for (int k = 0; k < 8; k++) Ut[row8][c8 + k] = v[k] * inv;
            }
            __syncthreads();
#pragma unroll 4
            for (int rr = 0; rr < 32; ++rr) {
                float4 t1 = *(const float4*)&Ut[rr][ty * 4];
                float4 t2 = *(const float4*)&Ut[rr][tx * 4];
                float ux[4] = {t1.x, t1.y, t1.z, t1.w};
                float ue[4] = {t2.x, t2.y, t2.z, t2.w};
#pragma unroll
                for (int a = 0; a < 4; a++)
#pragma unroll
                    for (int e = 0; e < 4; e++) su[a][e] = fmaf(ux[a], ue[e], su[a][e]);
            }
        }
        float* dst = tot + (size_t)p * 3 * 4096;
#pragma unroll
        for (int a = 0; a < 4; a++)
#pragma unroll
            for (int e = 0; e < 4; e++)
                atomicAdd(&dst[(ty * 4 + a) * 64 + tx * 4 + e], su[a][e]);
    } else {
        __shared__ __align__(16) float Wt[32][68];
        __shared__ __align__(16) float Vv[32][68];
        __shared__ float cm[64], ci[64];
        if (tid < 64) cm[tid] = stats[p * 128 + tid];
        else if (tid < 128) ci[tid - 64] = 1.0f / stats[p * 128 + tid];
        float sv[4][4] = {}, kv[4][4] = {};
        for (int sub = 0; sub < 4; ++sub) {
            int lb = chunk * 128 + sub * 32;
            __syncthreads();
            {
                size_t base = ((size_t)((b * SEQ + lb + row8) * NH + h)) * D + c8;
                const float4* vp = (const float4*)(V + base);
                const float4* ap = (const float4*)(vals + base);
                float4 v0 = vp[0], v1 = vp[1], a0 = ap[0], a1 = ap[1];
                float wv[8] = {v0.x, v0.y, v0.z, v0.w, v1.x, v1.y, v1.z, v1.w};
                float av[8] = {a0.x, a0.y, a0.z, a0.w, a1.x, a1.y, a1.z, a1.w};
#pragma unroll
                for (int k = 0; k < 8; k++) {
                    Wt[row8][c8 + k] = __expf(wv[k] - cm[c8 + k]) * ci[c8 + k];
                    Vv[row8][c8 + k] = av[k];
                }
            }
            __syncthreads();
#pragma unroll 4
            for (int rr = 0; rr < 32; ++rr) {
                float4 t1 = *(const float4*)&Wt[rr][ty * 4];
                float4 t2 = *(const float4*)&Wt[rr][tx * 4];
                float4 t3 = *(const float4*)&Vv[rr][tx * 4];
                float wx[4] = {t1.x, t1.y, t1.z, t1.w};
                float we[4] = {t2.x, t2.y, t2.z, t2.w};
                float ve[4] = {t3.x, t3.y, t3.z, t3.w};
#pragma unroll
                for (int a = 0; a < 4; a++)
#pragma unroll
                    for (int e = 0; e < 4; e++) {
                        sv[a][e] = fmaf(wx[a], we[e], sv[a][e]);
                        kv[a][e] = fmaf(wx[a], ve[e], kv[a][e]);
                    }
            }
        }
        float* dst = tot + (size_t)p * 3 * 4096;
#pragma unroll
        for (int a = 0; a < 4; a++)
#pragma unroll
            for (int e = 0; e < 4; e++) {
                int off = (ty * 4 + a) * 64 + tx * 4 + e;
                atomicAdd(&dst[4096 + off], sv[a][e]);
                atomicAdd(&dst[8192 + off], kv[a][e]);
            }
    }
}

// ---------------- fused: agf_out (x<32) + ortho (x==32) ----------------
__global__ __launch_bounds__(256) void agf_ortho(const float* __restrict__ U, const float* __restrict__ Sg,
                                                 const float* __restrict__ gam, const float* __restrict__ tot,
                                                 float* __restrict__ out) {
    int p = blockIdx.y;
    int tid = threadIdx.x;
    if (blockIdx.x == 32) {
        // ortho partial for pair p
        int b = p / NH;
        float s = 0.0f;
        for (int idx = tid; idx < 2 * 4096; idx += 256) {
            int m = idx >> 12;
            int i = idx & 4095;
            float v = tot[((size_t)p * 3 + m) * 4096 + i];
            float dg = ((i >> 6) == (i & 63)) ? 1.0f : 0.0f;
            s += fabsf(v - dg);
        }
#pragma unroll
        for (int o = 32; o > 0; o >>= 1) s += __shfl_xor(s, o);
        __shared__ float r4[4];
        if ((tid & 63) == 0) r4[tid >> 6] = s;
        __syncthreads();
        if (tid == 0) {
            float t = r4[0] + r4[1] + r4[2] + r4[3];
            atomicAdd(&out[LOSS_BASE + b], t * (1.0f / 16384.0f));
        }
        return;
    }
    int lt = blockIdx.x;                      // 0..31
    int b = p / NH, h = p % NH;
    __shared__ __align__(16) float kvs[64][68];
    __shared__ __align__(16) float ugs[64][68];
    const float* kvsrc = tot + (size_t)(p * 3 + 2) * 4096;
    for (int idx = tid; idx < 4096; idx += 256) kvs[idx >> 6][idx & 63] = kvsrc[idx];
    {
        int row = tid >> 2;                   // 0..63
        int c16 = (tid & 3) * 16;
        size_t ibase = ((size_t)((b * SEQ + lt * 64 + row) * NH + h)) * D + c16;
        const float4* up = (const float4*)(U + ibase);
        float uv[16];
#pragma unroll
        for (int k4 = 0; k4 < 4; k4++) {
            float4 t = up[k4];
            uv[k4 * 4 + 0] = t.x; uv[k4 * 4 + 1] = t.y; uv[k4 * 4 + 2] = t.z; uv[k4 * 4 + 3] = t.w;
        }
        float mx = uv[0];
#pragma unroll
        for (int k = 1; k < 16; k++) mx = fmaxf(mx, uv[k]);
        mx = fmaxf(mx, __shfl_xor(mx, 1));
        mx = fmaxf(mx, __shfl_xor(mx, 2));
        float sm = 0.0f;
#pragma unroll
        for (int k = 0; k < 16; k++) { uv[k] = __expf(uv[k] - mx); sm += uv[k]; }
        sm += __shfl_xor(sm, 1);
        sm += __shfl_xor(sm, 2);
        float inv = 1.0f / sm;
        const float4* sp = (const float4*)(Sg + ibase);
        float sg[16];
#pragma unroll
        for (int k4 = 0; k4 < 4; k4++) {
            float4 t = sp[k4];
            sg[k4 * 4 + 0] = t.x; sg[k4 * 4 + 1] = t.y; sg[k4 * 4 + 2] = t.z; sg[k4 * 4 + 3] = t.w;
        }
        float g0 = gam[0], g1 = gam[1], g2 = gam[2], g3 = gam[3];
#pragma unroll
        for (int k = 0; k < 16; k++) {
            float sig = 1.0f / (1.0f + __expf(-sg[k]));
            float x1 = 2.0f * sig;
            float x2 = 1.875f * sig * x1 - 0.75f;
            float x3 = 1.8666666666666667f * sig * x2 - 0.8f * x1;
            float gf = g0 + g1 * x1 + g2 * x2 + g3 * x3;
            ugs[row][c16 + k] = uv[k] * inv * gf;
        }
    }
    __syncthreads();
    int tx = tid & 15, ty = tid >> 4;
    float acc[4][4] = {};
#pragma unroll 8
    for (int x = 0; x < 64; x++) {
        float4 kt = *(const float4*)&kvs[x][tx * 4];
        float kb[4] = {kt.x, kt.y, kt.z, kt.w};
#pragma unroll
        for (int a = 0; a < 4; a++) {
            float ua = ugs[ty * 4 + a][x];
#pragma unroll
            for (int e = 0; e < 4; e++) acc[a][e] = fmaf(ua, kb[e], acc[a][e]);
        }
    }
#pragma unroll
    for (int a = 0; a < 4; a++)
#pragma unroll
        for (int e = 0; e < 4; e++)
            out[((size_t)(b * SEQ + lt * 64 + ty * 4 + a) * HOUT + h) * D + tx * 4 + e] = acc[a][e];
}

// ---------------- MFMA flash v2: K pre-converted bf16 hi/lo; V,P hi-only ----------------
#define LSTR 72   // ushort row stride (+8 pad)

__global__ __launch_bounds__(256, 4) void flash2(const unsigned short* __restrict__ Khi_g,
                                                 const unsigned short* __restrict__ Klo_g,
                                                 const float* __restrict__ Q, const float* __restrict__ V,
                                                 float* __restrict__ out) {
    int qt = blockIdx.x;                      // 0..31
    int p = blockIdx.y;                       // 0..15
    int b = p >> 2, h = p & 3;
    __shared__ __align__(16) unsigned short Khi[64 * LSTR], Klo[64 * LSTR];
    __shared__ __align__(16) unsigned short Vh[64 * LSTR];                 // transposed: [d][key]
    __shared__ __align__(16) unsigned short Ph[4][16 * LSTR];
    const int tid = threadIdx.x;
    const int w = tid >> 6, lane = tid & 63;
    const int lm = lane & 15, quad = lane >> 4;

    // ---- Q A-frags, hi/lo, scale 1/8 folded. A[m=lane&15][k=quad*8+j] ----
    bf16x8 qhi[2], qlo[2];
    {
        int row = qt * 64 + w * 16 + lm;
        const float* qp = Q + ((size_t)(b * SEQ + row) * NH + h) * D + quad * 8;
#pragma unroll
        for (int ks = 0; ks < 2; ks++) {
            float4 a0 = *(const float4*)(qp + ks * 32);
            float4 a1 = *(const float4*)(qp + ks * 32 + 4);
            float qq[8] = {a0.x, a0.y, a0.z, a0.w, a1.x, a1.y, a1.z, a1.w};
#pragma unroll
            for (int j = 0; j < 8; j++) {
                float xs = qq[j] * 0.125f;
                unsigned short hi = f2bf(xs);
                qhi[ks][j] = (short)hi;
                qlo[ks][j] = (short)f2bf(xs - bf2f(hi));
            }
        }
    }

    float mrun[4], lrun[4];
    f32x4 o[4];
#pragma unroll
    for (int r = 0; r < 4; r++) { mrun[r] = -INFINITY; lrun[r] = 0.0f; }
#pragma unroll
    for (int t = 0; t < 4; t++) o[t] = (f32x4){0.f, 0.f, 0.f, 0.f};

    for (int kt = 0; kt < SEQ / 64; ++kt) {
        __syncthreads();                      // previous iteration's reads complete
        {   // stage K hi/lo: pure bf16 copy (no conversion)
            int row = tid >> 2;
            int c0 = (tid & 3) * 16;
            size_t gb = ((size_t)p * SEQ + kt * 64 + row) * 64 + c0;
            us8 h0 = *(const us8*)(Khi_g + gb);
            us8 h1 = *(const us8*)(Khi_g + gb + 8);
            us8 l0 = *(const us8*)(Klo_g + gb);
            us8 l1 = *(const us8*)(Klo_g + gb + 8);
            *(us8*)&Khi[row * LSTR + c0] = h0;
            *(us8*)&Khi[row * LSTR + c0 + 8] = h1;
            *(us8*)&Klo[row * LSTR + c0] = l0;
            *(us8*)&Klo[row * LSTR + c0 + 8] = l1;
        }
        {   // stage V transposed [d][key], hi only, 4x4 register transpose
            int r0 = (tid & 15) * 4;          // key base
            int c0 = (tid >> 4) * 4;          // d base
            float vv[4][4];
#pragma unroll
            for (int i = 0; i < 4; i++) {
                float4 t = *(const float4*)(V + ((size_t)(b * SEQ + kt * 64 + r0 + i) * NH + h) * D + c0);
                vv[i][0] = t.x; vv[i][1] = t.y; vv[i][2] = t.z; vv[i][3] = t.w;
            }
#pragma unroll
            for (int c = 0; c < 4; c++) {
                us4 hv;
#pragma unroll
                for (int i = 0; i < 4; i++) hv[i] = f2bf(vv[i][c]);
                *(us4*)&Vh[(c0 + c) * LSTR + r0] = hv;
            }
        }
        __syncthreads();

        // ---- S = Q K^T : 3-pass (qh*kh + ql*kh + qh*kl); err ~ql*kl negligible ----
        f32x4 s[4];
#pragma unroll
        for (int t = 0; t < 4; t++) s[t] = (f32x4){0.f, 0.f, 0.f, 0.f};
#pragma unroll
        for (int t = 0; t < 4; t++) {
#pragma unroll
            for (int ks = 0; ks < 2; ks++) {
                int off = (t * 16 + lm) * LSTR + ks * 32 + quad * 8;
                bf16x8 kh = *(const bf16x8*)&Khi[off];
                bf16x8 kl = *(const bf16x8*)&Klo[off];
                s[t] = __builtin_amdgcn_mfma_f32_16x16x32_bf16(qhi[ks], kh, s[t], 0, 0, 0);
                s[t] = __builtin_amdgcn_mfma_f32_16x16x32_bf16(qlo[ks], kh, s[t], 0, 0, 0);
                s[t] = __builtin_amdgcn_mfma_f32_16x16x32_bf16(qhi[ks], kl, s[t], 0, 0, 0);
            }
        }

        // ---- online softmax (C-layout: row=quad*4+r, col=t*16+lm); P rounded to bf16,
        //      lsum accumulated over ROUNDED P so out = sum(p~ v)/sum(p~) ----
#pragma unroll
        for (int r = 0; r < 4; r++) {
            float rm = fmaxf(fmaxf(s[0][r], s[1][r]), fmaxf(s[2][r], s[3][r]));
            rm = fmaxf(rm, __shfl_xor(rm, 1));
            rm = fmaxf(rm, __shfl_xor(rm, 2));
            rm = fmaxf(rm, __shfl_xor(rm, 4));
            rm = fmaxf(rm, __shfl_xor(rm, 8));
            float mn = fmaxf(mrun[r], rm);
            float alpha = __expf(mrun[r] - mn);
            mrun[r] = mn;
            float rs = 0.0f;
#pragma unroll
            for (int t = 0; t < 4; t++) {
                unsigned short hi = f2bf(__expf(s[t][r] - mn));
                Ph[w][(quad * 4 + r) * LSTR + t * 16 + lm] = hi;
                rs += bf2f(hi);
            }
            rs += __shfl_xor(rs, 1);
            rs += __shfl_xor(rs, 2);
            rs += __shfl_xor(rs, 4);
            rs += __shfl_xor(rs, 8);
            lrun[r] = lrun[r] * alpha + rs;
#pragma unroll
            for (int t = 0; t < 4; t++) o[t][r] *= alpha;
        }
        // same-wave LDS write->read ordering handled by lgkmcnt (per-wave P region)

        // ---- O += P V (both hi-only) ----
        bf16x8 ph[2];
#pragma unroll
        for (int ks = 0; ks < 2; ks++)
            ph[ks] = *(const bf16x8*)&Ph[w][lm * LSTR + ks * 32 + quad * 8];
#pragma unroll
        for (int dt = 0; dt < 4; dt++) {
#pragma unroll
            for (int ks = 0; ks < 2; ks++) {
                bf16x8 vh = *(const bf16x8*)&Vh[(dt * 16 + lm) * LSTR + ks * 32 + quad * 8];
                o[dt] = __builtin_amdgcn_mfma_f32_16x16x32_bf16(ph[ks], vh, o[dt], 0, 0, 0);
            }
        }
    }

    // ---- epilogue ----
#pragma unroll
    for (int r = 0; r < 4; r++) {
        float inv = 1.0f / lrun[r];
        int row = qt * 64 + w * 16 + quad * 4 + r;
        float* op = out + ((size_t)(b * SEQ + row) * HOUT + 4 + h) * D + lm;
#pragma unroll
        for (int dt = 0; dt < 4; dt++) op[dt * 16] = o[dt][r] * inv;
    }
}

extern "C" void kernel_launch(void* const* d_in, const int* in_sizes, int n_in,
                              void* d_out, int out_size, void* d_ws, size_t ws_size,
                              hipStream_t stream) {
    (void)in_sizes; (void)n_in; (void)out_size; (void)ws_size;
    const float* U    = (const float*)d_in[0];
    const float* Sg   = (const float*)d_in[1];
    const float* V    = (const float*)d_in[2];
    const float* vals = (const float*)d_in[3];
    const float* Qs   = (const float*)d_in[4];
    const float* Ks   = (const float*)d_in[5];
    const float* Vv   = (const float*)d_in[6];
    const float* gam  = (const float*)d_in[7];
    float* out = (float*)d_out;

    float* tot   = (float*)d_ws;                       // NPAIR*3*4096
    float* stats = tot + TOT_ELEMS;                    // NPAIR*128
    float* vpart = stats + NPAIR * 128;                // NPAIR*8*128
    unsigned short* Khi = (unsigned short*)((float*)d_ws + WS_F32_HEAD);  // NPAIR*SEQ*64
    unsigned short* Klo = Khi + (size_t)NPAIR * SEQ * 64;

    prep<<<2048 + (TOT_ELEMS + 255) / 256, 256, 0, stream>>>(Ks, tot, Khi, Klo, out);
    vt_part<<<dim3(NPAIR, 8), 256, 0, stream>>>(V, vpart);
    vt_merge<<<NPAIR, 64, 0, stream>>>(vpart, stats);
    gram_uv<<<dim3(16, NPAIR, 2), 256, 0, stream>>>(U, V, vals, stats, tot);
    agf_ortho<<<dim3(33, NPAIR), 256, 0, stream>>>(U, Sg, gam, tot, out);
    flash2<<<dim3(SEQ / 64, NPAIR), 256, 0, stream>>>(Khi, Klo, Qs, Vv, out);
}

// Round 6
// 248.039 us; speedup vs baseline: 2.1390x; 1.1879x over previous
//
#include <hip/hip_runtime.h>
#include <hip/hip_bf16.h>

#define BB 4
#define SEQ 2048
#define NH 4
#define D 64
#define NPAIR (BB*NH)
#define HOUT 8
#define LOSS_BASE ((size_t)BB * SEQ * HOUT * D)

#define TOT_ELEMS (NPAIR * 3 * 4096)
#define KSZ ((size_t)NPAIR * SEQ * 64)

typedef __attribute__((ext_vector_type(8))) short bf16x8;
typedef __attribute__((ext_vector_type(4))) float f32x4;
typedef __attribute__((ext_vector_type(8))) unsigned short us8;
typedef __attribute__((ext_vector_type(4))) unsigned short us4;

__device__ __forceinline__ unsigned short f2bf(float x) {
    union { float f; unsigned u; } v; v.f = x;
    unsigned r = v.u + 0x7fffu + ((v.u >> 16) & 1u);
    return (unsigned short)(r >> 16);
}
__device__ __forceinline__ float bf2f(unsigned short u) {
    union { unsigned u; float f; } v; v.u = ((unsigned)u) << 16; return v.f;
}

// ---------------- prep: K->bf16 hi/lo, Vsm->bf16, vt_part stats, zero tot/loss ----------------
// blocks [0,2048): K+Vsm convert; [2048,2176): vt_part; [2176,2944): zero tot
__global__ __launch_bounds__(256) void prep(const float* __restrict__ K, const float* __restrict__ Vsm,
                                            const float* __restrict__ Vagf,
                                            unsigned short* __restrict__ Khi, unsigned short* __restrict__ Klo,
                                            unsigned short* __restrict__ Vbf,
                                            float* __restrict__ vpart, float* __restrict__ tot,
                                            float* __restrict__ out) {
    int blk = blockIdx.x;
    int tid = threadIdx.x;
    if (blk < 2048) {
        int i = (blk * 256 + tid) * 4;        // over [p][l][d] = [16][2048][64]
        int p = i >> 17;
        int rem = i & 131071;
        int l = rem >> 6, d = rem & 63;
        int b = p >> 2, h = p & 3;
        size_t src = (((size_t)(b * SEQ + l) * NH + h) << 6) + d;
        float4 kv = *(const float4*)(K + src);
        float4 vv = *(const float4*)(Vsm + src);
        float kk[4] = {kv.x, kv.y, kv.z, kv.w};
        float vf[4] = {vv.x, vv.y, vv.z, vv.w};
        us4 hi, lo, vb;
#pragma unroll
        for (int k = 0; k < 4; k++) {
            unsigned short h16 = f2bf(kk[k]);
            hi[k] = h16;
            lo[k] = f2bf(kk[k] - bf2f(h16));
            vb[k] = f2bf(vf[k]);
        }
        *(us4*)(Khi + i) = hi;
        *(us4*)(Klo + i) = lo;
        *(us4*)(Vbf + i) = vb;
    } else if (blk < 2176) {
        // vt_part: per (p, seg of 256 l): column max + sumexp of Vagf
        int v = blk - 2048;
        int p = v >> 3, seg = v & 7;
        int b = p / NH, h = p % NH;
        int x = tid & 63;
        int c = tid >> 6;                     // 0..3
        __shared__ float red[4][64];
        __shared__ float cmax[64];
        const size_t base = ((size_t)(b * SEQ + seg * 256) * NH + h) * D + x;
        const int stride = NH * D;
        float m = -INFINITY;
        for (int l = c; l < 256; l += 4) m = fmaxf(m, Vagf[base + (size_t)l * stride]);
        red[c][x] = m;
        __syncthreads();
        if (c == 0) cmax[x] = fmaxf(fmaxf(red[0][x], red[1][x]), fmaxf(red[2][x], red[3][x]));
        __syncthreads();
        float mm = cmax[x];
        float s = 0.0f;
        for (int l = c; l < 256; l += 4) s += __expf(Vagf[base + (size_t)l * stride] - mm);
        __syncthreads();
        red[c][x] = s;
        __syncthreads();
        if (c == 0) {
            float ss = red[0][x] + red[1][x] + red[2][x] + red[3][x];
            vpart[(size_t)(p * 8 + seg) * 128 + x] = cmax[x];
            vpart[(size_t)(p * 8 + seg) * 128 + 64 + x] = ss;
        }
    } else {
        int i = (blk - 2176) * 256 + tid;
        if (i < TOT_ELEMS) tot[i] = 0.0f;
        if (blk == 2176 && tid < BB) out[LOSS_BASE + tid] = 0.0f;
    }
}

// ---------------- fused grams: z=0 -> SU = Uh^T Uh ; z=1 -> SV/KV (stats merged inline) ----------------
__global__ __launch_bounds__(256) void gram_uv(const float* __restrict__ U, const float* __restrict__ V,
                                               const float* __restrict__ vals, const float* __restrict__ vpart,
                                               float* __restrict__ tot) {
    int chunk = blockIdx.x;                   // 0..15 (128 rows each)
    int p = blockIdx.y;
    int b = p / NH, h = p % NH;
    int tid = threadIdx.x;
    int tx = tid & 15, ty = tid >> 4;
    int row8 = tid >> 3;                      // 0..31
    int c8 = (tid & 7) * 8;

    if (blockIdx.z == 0) {
        __shared__ __align__(16) float Ut[32][68];
        float su[4][4] = {};
        for (int sub = 0; sub < 4; ++sub) {
            int lb = chunk * 128 + sub * 32;
            __syncthreads();
            {
                const float4* src = (const float4*)(U + ((size_t)((b * SEQ + lb + row8) * NH + h)) * D + c8);
                float4 q0 = src[0], q1 = src[1];
                float v[8] = {q0.x, q0.y, q0.z, q0.w, q1.x, q1.y, q1.z, q1.w};
                float mx = v[0];
#pragma unroll
                for (int k = 1; k < 8; k++) mx = fmaxf(mx, v[k]);
                mx = fmaxf(mx, __shfl_xor(mx, 1));
                mx = fmaxf(mx, __shfl_xor(mx, 2));
                mx = fmaxf(mx, __shfl_xor(mx, 4));
                float sm = 0.0f;
#pragma unroll
                for (int k = 0; k < 8; k++) { v[k] = __expf(v[k] - mx); sm += v[k]; }
                sm += __shfl_xor(sm, 1);
                sm += __shfl_xor(sm, 2);
                sm += __shfl_xor(sm, 4);
                float inv = 1.0f / sm;
#pragma unroll
                for (int k = 0; k < 8; k++) Ut[row8][c8 + k] = v[k] * inv;
            }
            __syncthreads();
#pragma unroll 4
            for (int rr = 0; rr < 32; ++rr) {
                float4 t1 = *(const float4*)&Ut[rr][ty * 4];
                float4 t2 = *(const float4*)&Ut[rr][tx * 4];
                float ux[4] = {t1.x, t1.y, t1.z, t1.w};
                float ue[4] = {t2.x, t2.y, t2.z, t2.w};
#pragma unroll
                for (int a = 0; a < 4; a++)
#pragma unroll
                    for (int e = 0; e < 4; e++) su[a][e] = fmaf(ux[a], ue[e], su[a][e]);
            }
        }
        float* dst = tot + (size_t)p * 3 * 4096;
#pragma unroll
        for (int a = 0; a < 4; a++)
#pragma unroll
            for (int e = 0; e < 4; e++)
                atomicAdd(&dst[(ty * 4 + a) * 64 + tx * 4 + e], su[a][e]);
    } else {
        __shared__ __align__(16) float Wt[32][68];
        __shared__ __align__(16) float Vv[32][68];
        __shared__ float cm[64], ci[64];
        if (tid < 64) {
            float M = -INFINITY;
#pragma unroll
            for (int s = 0; s < 8; s++) M = fmaxf(M, vpart[(size_t)(p * 8 + s) * 128 + tid]);
            float S = 0.0f;
#pragma unroll
            for (int s = 0; s < 8; s++)
                S += vpart[(size_t)(p * 8 + s) * 128 + 64 + tid] *
                     __expf(vpart[(size_t)(p * 8 + s) * 128 + tid] - M);
            cm[tid] = M;
            ci[tid] = 1.0f / S;
        }
        float sv[4][4] = {}, kv[4][4] = {};
        for (int sub = 0; sub < 4; ++sub) {
            int lb = chunk * 128 + sub * 32;
            __syncthreads();
            {
                size_t base = ((size_t)((b * SEQ + lb + row8) * NH + h)) * D + c8;
                const float4* vp = (const float4*)(V + base);
                const float4* ap = (const float4*)(vals + base);
                float4 v0 = vp[0], v1 = vp[1], a0 = ap[0], a1 = ap[1];
                float wv[8] = {v0.x, v0.y, v0.z, v0.w, v1.x, v1.y, v1.z, v1.w};
                float av[8] = {a0.x, a0.y, a0.z, a0.w, a1.x, a1.y, a1.z, a1.w};
#pragma unroll
                for (int k = 0; k < 8; k++) {
                    Wt[row8][c8 + k] = __expf(wv[k] - cm[c8 + k]) * ci[c8 + k];
                    Vv[row8][c8 + k] = av[k];
                }
            }
            __syncthreads();
#pragma unroll 4
            for (int rr = 0; rr < 32; ++rr) {
                float4 t1 = *(const float4*)&Wt[rr][ty * 4];
                float4 t2 = *(const float4*)&Wt[rr][tx * 4];
                float4 t3 = *(const float4*)&Vv[rr][tx * 4];
                float wx[4] = {t1.x, t1.y, t1.z, t1.w};
                float we[4] = {t2.x, t2.y, t2.z, t2.w};
                float ve[4] = {t3.x, t3.y, t3.z, t3.w};
#pragma unroll
                for (int a = 0; a < 4; a++)
#pragma unroll
                    for (int e = 0; e < 4; e++) {
                        sv[a][e] = fmaf(wx[a], we[e], sv[a][e]);
                        kv[a][e] = fmaf(wx[a], ve[e], kv[a][e]);
                    }
            }
        }
        float* dst = tot + (size_t)p * 3 * 4096;
#pragma unroll
        for (int a = 0; a < 4; a++)
#pragma unroll
            for (int e = 0; e < 4; e++) {
                int off = (ty * 4 + a) * 64 + tx * 4 + e;
                atomicAdd(&dst[4096 + off], sv[a][e]);
                atomicAdd(&dst[8192 + off], kv[a][e]);
            }
    }
}

// ---------------- fused: agf_out (x<32) + ortho (x==32) ----------------
__global__ __launch_bounds__(256) void agf_ortho(const float* __restrict__ U, const float* __restrict__ Sg,
                                                 const float* __restrict__ gam, const float* __restrict__ tot,
                                                 float* __restrict__ out) {
    int p = blockIdx.y;
    int tid = threadIdx.x;
    if (blockIdx.x == 32) {
        int b = p / NH;
        float s = 0.0f;
        for (int idx = tid; idx < 2 * 4096; idx += 256) {
            int m = idx >> 12;
            int i = idx & 4095;
            float v = tot[((size_t)p * 3 + m) * 4096 + i];
            float dg = ((i >> 6) == (i & 63)) ? 1.0f : 0.0f;
            s += fabsf(v - dg);
        }
#pragma unroll
        for (int o = 32; o > 0; o >>= 1) s += __shfl_xor(s, o);
        __shared__ float r4[4];
        if ((tid & 63) == 0) r4[tid >> 6] = s;
        __syncthreads();
        if (tid == 0) {
            float t = r4[0] + r4[1] + r4[2] + r4[3];
            atomicAdd(&out[LOSS_BASE + b], t * (1.0f / 16384.0f));
        }
        return;
    }
    int lt = blockIdx.x;                      // 0..31
    int b = p / NH, h = p % NH;
    __shared__ __align__(16) float kvs[64][68];
    __shared__ __align__(16) float ugs[64][68];
    const float* kvsrc = tot + (size_t)(p * 3 + 2) * 4096;
    for (int idx = tid; idx < 4096; idx += 256) kvs[idx >> 6][idx & 63] = kvsrc[idx];
    {
        int row = tid >> 2;                   // 0..63
        int c16 = (tid & 3) * 16;
        size_t ibase = ((size_t)((b * SEQ + lt * 64 + row) * NH + h)) * D + c16;
        const float4* up = (const float4*)(U + ibase);
        float uv[16];
#pragma unroll
        for (int k4 = 0; k4 < 4; k4++) {
            float4 t = up[k4];
            uv[k4 * 4 + 0] = t.x; uv[k4 * 4 + 1] = t.y; uv[k4 * 4 + 2] = t.z; uv[k4 * 4 + 3] = t.w;
        }
        float mx = uv[0];
#pragma unroll
        for (int k = 1; k < 16; k++) mx = fmaxf(mx, uv[k]);
        mx = fmaxf(mx, __shfl_xor(mx, 1));
        mx = fmaxf(mx, __shfl_xor(mx, 2));
        float sm = 0.0f;
#pragma unroll
        for (int k = 0; k < 16; k++) { uv[k] = __expf(uv[k] - mx); sm += uv[k]; }
        sm += __shfl_xor(sm, 1);
        sm += __shfl_xor(sm, 2);
        float inv = 1.0f / sm;
        const float4* sp = (const float4*)(Sg + ibase);
        float sg[16];
#pragma unroll
        for (int k4 = 0; k4 < 4; k4++) {
            float4 t = sp[k4];
            sg[k4 * 4 + 0] = t.x; sg[k4 * 4 + 1] = t.y; sg[k4 * 4 + 2] = t.z; sg[k4 * 4 + 3] = t.w;
        }
        float g0 = gam[0], g1 = gam[1], g2 = gam[2], g3 = gam[3];
#pragma unroll
        for (int k = 0; k < 16; k++) {
            float sig = 1.0f / (1.0f + __expf(-sg[k]));
            float x1 = 2.0f * sig;
            float x2 = 1.875f * sig * x1 - 0.75f;
            float x3 = 1.8666666666666667f * sig * x2 - 0.8f * x1;
            float gf = g0 + g1 * x1 + g2 * x2 + g3 * x3;
            ugs[row][c16 + k] = uv[k] * inv * gf;
        }
    }
    __syncthreads();
    int tx = tid & 15, ty = tid >> 4;
    float acc[4][4] = {};
#pragma unroll 8
    for (int x = 0; x < 64; x++) {
        float4 kt = *(const float4*)&kvs[x][tx * 4];
        float kb[4] = {kt.x, kt.y, kt.z, kt.w};
#pragma unroll
        for (int a = 0; a < 4; a++) {
            float ua = ugs[ty * 4 + a][x];
#pragma unroll
            for (int e = 0; e < 4; e++) acc[a][e] = fmaf(ua, kb[e], acc[a][e]);
        }
    }
#pragma unroll
    for (int a = 0; a < 4; a++)
#pragma unroll
        for (int e = 0; e < 4; e++)
            out[((size_t)(b * SEQ + lt * 64 + ty * 4 + a) * HOUT + h) * D + tx * 4 + e] = acc[a][e];
}

// ---------------- MFMA flash v3: fixed-max softmax, split-K x2 ----------------
#define LSTR 72   // ushort row stride
#define FIXM 10.0f

__global__ __launch_bounds__(256, 4) void flash3(const unsigned short* __restrict__ Khi_g,
                                                 const unsigned short* __restrict__ Klo_g,
                                                 const unsigned short* __restrict__ Vbf,
                                                 const float* __restrict__ Q,
                                                 float* __restrict__ Opart, float* __restrict__ lpart) {
    int qt = blockIdx.x;                      // 0..31
    int p = blockIdx.y;                       // 0..15
    int half = blockIdx.z;                    // 0..1
    int b = p >> 2, h = p & 3;
    __shared__ __align__(16) unsigned short Khi[64 * LSTR], Klo[64 * LSTR];
    __shared__ __align__(16) unsigned short Vh[64 * LSTR];                 // transposed: [d][key]
    __shared__ __align__(16) unsigned short Ph[4][16 * LSTR];
    const int tid = threadIdx.x;
    const int w = tid >> 6, lane = tid & 63;
    const int lm = lane & 15, quad = lane >> 4;

    // ---- Q A-frags, hi/lo, scale 1/8 folded ----
    bf16x8 qhi[2], qlo[2];
    {
        int row = qt * 64 + w * 16 + lm;
        const float* qp = Q + ((size_t)(b * SEQ + row) * NH + h) * D + quad * 8;
#pragma unroll
        for (int ks = 0; ks < 2; ks++) {
            float4 a0 = *(const float4*)(qp + ks * 32);
            float4 a1 = *(const float4*)(qp + ks * 32 + 4);
            float qq[8] = {a0.x, a0.y, a0.z, a0.w, a1.x, a1.y, a1.z, a1.w};
#pragma unroll
            for (int j = 0; j < 8; j++) {
                float xs = qq[j] * 0.125f;
                unsigned short hi = f2bf(xs);
                qhi[ks][j] = (short)hi;
                qlo[ks][j] = (short)f2bf(xs - bf2f(hi));
            }
        }
    }

    float rsum[4];
    f32x4 o[4];
#pragma unroll
    for (int r = 0; r < 4; r++) rsum[r] = 0.0f;
#pragma unroll
    for (int t = 0; t < 4; t++) o[t] = (f32x4){0.f, 0.f, 0.f, 0.f};

    for (int it = 0; it < 16; ++it) {
        int kt = half * 16 + it;
        __syncthreads();                      // previous iteration's K/V reads complete
        {   // stage K hi/lo: pure bf16 copy
            int row = tid >> 2;
            int c0 = (tid & 3) * 16;
            size_t gb = ((size_t)p * SEQ + kt * 64 + row) * 64 + c0;
            us8 h0 = *(const us8*)(Khi_g + gb);
            us8 h1 = *(const us8*)(Khi_g + gb + 8);
            us8 l0 = *(const us8*)(Klo_g + gb);
            us8 l1 = *(const us8*)(Klo_g + gb + 8);
            *(us8*)&Khi[row * LSTR + c0] = h0;
            *(us8*)&Khi[row * LSTR + c0 + 8] = h1;
            *(us8*)&Klo[row * LSTR + c0] = l0;
            *(us8*)&Klo[row * LSTR + c0 + 8] = l1;
        }
        {   // stage V transposed [d][key]: 4x4 u16 register transpose from pre-converted bf16
            int r0 = (tid & 15) * 4;          // key base
            int c0 = (tid >> 4) * 4;          // d base
            us4 vv[4];
#pragma unroll
            for (int i = 0; i < 4; i++)
                vv[i] = *(const us4*)(Vbf + ((size_t)p * SEQ + kt * 64 + r0 + i) * 64 + c0);
#pragma unroll
            for (int c = 0; c < 4; c++) {
                us4 col;
#pragma unroll
                for (int i = 0; i < 4; i++) col[i] = vv[i][c];
                *(us4*)&Vh[(c0 + c) * LSTR + r0] = col;
            }
        }
        __syncthreads();

        // ---- S = Q K^T : 3-pass ----
        f32x4 s[4];
#pragma unroll
        for (int t = 0; t < 4; t++) s[t] = (f32x4){0.f, 0.f, 0.f, 0.f};
#pragma unroll
        for (int t = 0; t < 4; t++) {
#pragma unroll
            for (int ks = 0; ks < 2; ks++) {
                int off = (t * 16 + lm) * LSTR + ks * 32 + quad * 8;
                bf16x8 kh = *(const bf16x8*)&Khi[off];
                bf16x8 kl = *(const bf16x8*)&Klo[off];
                s[t] = __builtin_amdgcn_mfma_f32_16x16x32_bf16(qhi[ks], kh, s[t], 0, 0, 0);
                s[t] = __builtin_amdgcn_mfma_f32_16x16x32_bf16(qlo[ks], kh, s[t], 0, 0, 0);
                s[t] = __builtin_amdgcn_mfma_f32_16x16x32_bf16(qhi[ks], kl, s[t], 0, 0, 0);
            }
        }

        // ---- fixed-max exp: p = exp(s - FIXM); no reductions, no rescale ----
#pragma unroll
        for (int t = 0; t < 4; t++)
#pragma unroll
            for (int r = 0; r < 4; r++) {
                unsigned short hi = f2bf(__expf(s[t][r] - FIXM));
                Ph[w][(quad * 4 + r) * LSTR + t * 16 + lm] = hi;
                rsum[r] += bf2f(hi);
            }
        // same-wave LDS write->read ordering handled by lgkmcnt (per-wave P region)

        // ---- O += P V ----
        bf16x8 ph[2];
#pragma unroll
        for (int ks = 0; ks < 2; ks++)
            ph[ks] = *(const bf16x8*)&Ph[w][lm * LSTR + ks * 32 + quad * 8];
#pragma unroll
        for (int dt = 0; dt < 4; dt++) {
#pragma unroll
            for (int ks = 0; ks < 2; ks++) {
                bf16x8 vh = *(const bf16x8*)&Vh[(dt * 16 + lm) * LSTR + ks * 32 + quad * 8];
                o[dt] = __builtin_amdgcn_mfma_f32_16x16x32_bf16(ph[ks], vh, o[dt], 0, 0, 0);
            }
        }
    }

    // ---- epilogue: reduce rsum across the 16 lanes of each row, write partials ----
#pragma unroll
    for (int r = 0; r < 4; r++) {
        float rs = rsum[r];
        rs += __shfl_xor(rs, 1);
        rs += __shfl_xor(rs, 2);
        rs += __shfl_xor(rs, 4);
        rs += __shfl_xor(rs, 8);
        int row = qt * 64 + w * 16 + quad * 4 + r;
        size_t obase = ((size_t)(half * NPAIR + p) * SEQ + row) * 64;
#pragma unroll
        for (int dt = 0; dt < 4; dt++) Opart[obase + dt * 16 + lm] = o[dt][r];
        if (lm == 0) lpart[(size_t)(half * NPAIR + p) * SEQ + row] = rs;
    }
}

// ---------------- merge split-K partials ----------------
__global__ __launch_bounds__(256) void smerge(const float* __restrict__ Opart, const float* __restrict__ lpart,
                                              float* __restrict__ out) {
    int idx = blockIdx.x * 256 + threadIdx.x;   // over [p][l][d/4] = 16*2048*16
    int p = idx >> 15;
    int rem = idx & 32767;
    int l = rem >> 4, dq = rem & 15;
    int b = p >> 2, h = p & 3;
    size_t o0 = ((size_t)p * SEQ + l) * 64 + dq * 4;
    size_t o1 = ((size_t)(NPAIR + p) * SEQ + l) * 64 + dq * 4;
    f32x4 a = *(const f32x4*)(Opart + o0);
    f32x4 c = *(const f32x4*)(Opart + o1);
    float inv = 1.0f / (lpart[(size_t)p * SEQ + l] + lpart[(size_t)(NPAIR + p) * SEQ + l]);
    f32x4 res = (a + c) * inv;
    *(f32x4*)(out + ((size_t)(b * SEQ + l) * HOUT + 4 + h) * D + dq * 4) = res;
}

extern "C" void kernel_launch(void* const* d_in, const int* in_sizes, int n_in,
                              void* d_out, int out_size, void* d_ws, size_t ws_size,
                              hipStream_t stream) {
    (void)in_sizes; (void)n_in; (void)out_size; (void)ws_size;
    const float* U    = (const float*)d_in[0];
    const float* Sg   = (const float*)d_in[1];
    const float* V    = (const float*)d_in[2];
    const float* vals = (const float*)d_in[3];
    const float* Qs   = (const float*)d_in[4];
    const float* Ks   = (const float*)d_in[5];
    const float* Vv   = (const float*)d_in[6];
    const float* gam  = (const float*)d_in[7];
    float* out = (float*)d_out;

    float* tot   = (float*)d_ws;                        // NPAIR*3*4096 f32
    float* vpart = tot + TOT_ELEMS;                     // NPAIR*8*128 f32
    unsigned short* Khi = (unsigned short*)(vpart + NPAIR * 8 * 128);
    unsigned short* Klo = Khi + KSZ;
    unsigned short* Vbf = Klo + KSZ;
    float* Opart = (float*)(Vbf + KSZ);                 // 2*NPAIR*SEQ*64 f32
    float* lpart = Opart + (size_t)2 * NPAIR * SEQ * 64;// 2*NPAIR*SEQ f32

    prep<<<2944, 256, 0, stream>>>(Ks, Vv, V, Khi, Klo, Vbf, vpart, tot, out);
    gram_uv<<<dim3(16, NPAIR, 2), 256, 0, stream>>>(U, V, vals, vpart, tot);
    agf_ortho<<<dim3(33, NPAIR), 256, 0, stream>>>(U, Sg, gam, tot, out);
    flash3<<<dim3(SEQ / 64, NPAIR, 2), 256, 0, stream>>>(Khi, Klo, Vbf, Qs, Opart, lpart);
    smerge<<<(NPAIR * SEQ * 16) / 256, 256, 0, stream>>>(Opart, lpart, out);
}

// Round 7
// 180.297 us; speedup vs baseline: 2.9427x; 1.3757x over previous
//
#include <hip/hip_runtime.h>
#include <hip/hip_bf16.h>

#define BB 4
#define SEQ 2048
#define NH 4
#define D 64
#define NPAIR 16
#define HOUT 8
#define LOSS_BASE ((size_t)BB * SEQ * HOUT * D)

// ---- float ws layout ----
#define OFF_PART 0                            // part[4][16][3][4096]
#define N_PART   (4 * 16 * 3 * 4096)
#define OFF_SPART (OFF_PART + N_PART)         // Spart[16][32][64]
#define N_SPART  (16 * 32 * 64)
#define OFF_LPART (OFF_SPART + N_SPART)       // lpart[2][16][2048]
#define N_LPART  (2 * 16 * 2048)
#define OFF_OPART (OFF_LPART + N_LPART)       // Opart[2][16][2048][64]
#define N_OPART  (2 * 16 * 2048 * 64)
#define OFF_US   (OFF_OPART + N_OPART)        // ushort arrays below
// ushort arrays, each [16][*] of 2048*64 elems: Khi, VbfT, UhT, EhiT, EloT, valsT
#define USZ ((size_t)16 * 2048 * 64)

typedef __attribute__((ext_vector_type(8))) short bf16x8;
typedef __attribute__((ext_vector_type(4))) float f32x4;
typedef __attribute__((ext_vector_type(8))) unsigned short us8;
typedef __attribute__((ext_vector_type(4))) unsigned short us4;

__device__ __forceinline__ unsigned short f2bf(float x) {
    union { float f; unsigned u; } v; v.f = x;
    unsigned r = v.u + 0x7fffu + ((v.u >> 16) & 1u);
    return (unsigned short)(r >> 16);
}
__device__ __forceinline__ float bf2f(unsigned short u) {
    union { unsigned u; float f; } v; v.u = ((unsigned)u) << 16; return v.f;
}
__device__ __forceinline__ void load16(const float* p, float* v) {
    const float4* q = (const float4*)p;
    float4 a = q[0], b = q[1], c = q[2], d = q[3];
    v[0]=a.x; v[1]=a.y; v[2]=a.z; v[3]=a.w;
    v[4]=b.x; v[5]=b.y; v[6]=b.z; v[7]=b.w;
    v[8]=c.x; v[9]=c.y; v[10]=c.z; v[11]=c.w;
    v[12]=d.x; v[13]=d.y; v[14]=d.z; v[15]=d.w;
}
__device__ __forceinline__ void wr_bf16x16(unsigned short* dst, const float* v) {
    us8 w0, w1;
#pragma unroll
    for (int i = 0; i < 8; i++) { w0[i] = f2bf(v[i]); w1[i] = f2bf(v[8 + i]); }
    *(us8*)dst = w0; *(us8*)(dst + 8) = w1;
}

// ================= prep: all input conversions / transposes =================
// grid (32 ltiles, 16 p), 256 thr
__global__ __launch_bounds__(256) void prep(const float* __restrict__ U, const float* __restrict__ Vagf,
                                            const float* __restrict__ vals, const float* __restrict__ Ksm,
                                            const float* __restrict__ Vsm,
                                            float* __restrict__ ws, unsigned short* __restrict__ usb,
                                            float* __restrict__ out) {
    int lt = blockIdx.x, p = blockIdx.y;
    int b = p >> 2, h = p & 3;
    int tid = threadIdx.x;
    int r = tid >> 2;             // row (l for loads; d for transposed writes)
    int c4 = tid & 3;
    int c0 = c4 * 16;
    __shared__ float T[64][68];
    unsigned short* Khi   = usb;
    unsigned short* VbfT  = usb + USZ;
    unsigned short* UhT   = usb + 2 * USZ;
    unsigned short* EhiT  = usb + 3 * USZ;
    unsigned short* EloT  = usb + 4 * USZ;
    unsigned short* valsT = usb + 5 * USZ;
    float* Spart = ws + OFF_SPART;

    const size_t gbase = ((size_t)(b * SEQ + lt * 64 + r) * NH + h) * D + c0;
    const size_t tbase = ((size_t)p * 64 + r) * 2048 + lt * 64 + c0;   // transposed out: row d=r
    float v[16], e[16];

    // ---- 1: U -> row softmax -> UhT (transposed bf16)
    load16(U + gbase, v);
    float mx = v[0];
#pragma unroll
    for (int k = 1; k < 16; k++) mx = fmaxf(mx, v[k]);
    mx = fmaxf(mx, __shfl_xor(mx, 1));
    mx = fmaxf(mx, __shfl_xor(mx, 2));
    float sm = 0.0f;
#pragma unroll
    for (int k = 0; k < 16; k++) { v[k] = __expf(v[k] - mx); sm += v[k]; }
    sm += __shfl_xor(sm, 1);
    sm += __shfl_xor(sm, 2);
    float inv = 1.0f / sm;
#pragma unroll
    for (int k = 0; k < 16; k++) T[r][c0 + k] = v[k] * inv;
    __syncthreads();
#pragma unroll
    for (int k = 0; k < 16; k++) e[k] = T[c0 + k][r];
    wr_bf16x16(UhT + tbase, e);
    __syncthreads();

    // ---- 2: E = exp(Vagf) -> Ehi/Elo (transposed) + column sums Spart
    load16(Vagf + gbase, v);
#pragma unroll
    for (int k = 0; k < 16; k++) T[r][c0 + k] = __expf(v[k]);
    __syncthreads();
    float ssum = 0.0f;
#pragma unroll
    for (int k = 0; k < 16; k++) { e[k] = T[c0 + k][r]; ssum += e[k]; }
    ssum += __shfl_xor(ssum, 1);
    ssum += __shfl_xor(ssum, 2);
    if (c4 == 0) Spart[(p * 32 + lt) * 64 + r] = ssum;
    {
        us8 h0, h1, l0, l1;
#pragma unroll
        for (int i = 0; i < 8; i++) {
            unsigned short hh = f2bf(e[i]);
            h0[i] = hh; l0[i] = f2bf(e[i] - bf2f(hh));
            unsigned short h2 = f2bf(e[8 + i]);
            h1[i] = h2; l1[i] = f2bf(e[8 + i] - bf2f(h2));
        }
        *(us8*)(EhiT + tbase) = h0; *(us8*)(EhiT + tbase + 8) = h1;
        *(us8*)(EloT + tbase) = l0; *(us8*)(EloT + tbase + 8) = l1;
    }
    __syncthreads();

    // ---- 3: vals -> valsT (transposed bf16)
    load16(vals + gbase, v);
#pragma unroll
    for (int k = 0; k < 16; k++) T[r][c0 + k] = v[k];
    __syncthreads();
#pragma unroll
    for (int k = 0; k < 16; k++) e[k] = T[c0 + k][r];
    wr_bf16x16(valsT + tbase, e);
    __syncthreads();

    // ---- 4: Vsm -> VbfT (transposed bf16)
    load16(Vsm + gbase, v);
#pragma unroll
    for (int k = 0; k < 16; k++) T[r][c0 + k] = v[k];
    __syncthreads();
#pragma unroll
    for (int k = 0; k < 16; k++) e[k] = T[c0 + k][r];
    wr_bf16x16(VbfT + tbase, e);

    // ---- 5: K -> Khi (row-major bf16 hi)
    load16(Ksm + gbase, v);
    wr_bf16x16(Khi + ((size_t)(p * SEQ + lt * 64 + r)) * 64 + c0, v);

    if (lt == 0 && p == 0 && tid < BB) out[LOSS_BASE + tid] = 0.0f;
}

// ================= gram: MFMA split-K partials (no atomics) =================
// grid (4 splits, 16 p), 256 thr. part[(split*16+p)*3*4096 + g*4096 + d*64 + e]
__global__ __launch_bounds__(256) void gram(const unsigned short* __restrict__ usb,
                                            float* __restrict__ part) {
    int split = blockIdx.x, p = blockIdx.y;
    int tid = threadIdx.x;
    int w = tid >> 6, lane = tid & 63, lm = lane & 15, quad = lane >> 4;
    const unsigned short* UhT   = usb + 2 * USZ;
    const unsigned short* EhiT  = usb + 3 * USZ;
    const unsigned short* EloT  = usb + 4 * USZ;
    const unsigned short* valsT = usb + 5 * USZ;
    __shared__ __align__(16) unsigned short Ut[64 * 40], Eh[64 * 40], El[64 * 40], Vt[64 * 40];
    f32x4 su[4], sv[4], kv[4];
#pragma unroll
    for (int i = 0; i < 4; i++) { su[i] = (f32x4){0,0,0,0}; sv[i] = (f32x4){0,0,0,0}; kv[i] = (f32x4){0,0,0,0}; }
    int srow = tid >> 2;
    int sseg = (tid & 3) * 8;

    for (int step = 0; step < 16; ++step) {
        int l0 = split * 512 + step * 32;
        __syncthreads();
        size_t gb = ((size_t)p * 64 + srow) * 2048 + l0 + sseg;
        *(us8*)&Ut[srow * 40 + sseg] = *(const us8*)(UhT + gb);
        *(us8*)&Eh[srow * 40 + sseg] = *(const us8*)(EhiT + gb);
        *(us8*)&El[srow * 40 + sseg] = *(const us8*)(EloT + gb);
        *(us8*)&Vt[srow * 40 + sseg] = *(const us8*)(valsT + gb);
        __syncthreads();
        int ao = (w * 16 + lm) * 40 + quad * 8;
        bf16x8 au  = *(const bf16x8*)&Ut[ao];
        bf16x8 aeh = *(const bf16x8*)&Eh[ao];
        bf16x8 ael = *(const bf16x8*)&El[ao];
#pragma unroll
        for (int nt = 0; nt < 4; nt++) {
            int bo = (nt * 16 + lm) * 40 + quad * 8;
            bf16x8 bu  = *(const bf16x8*)&Ut[bo];
            bf16x8 beh = *(const bf16x8*)&Eh[bo];
            bf16x8 bv  = *(const bf16x8*)&Vt[bo];
            su[nt] = __builtin_amdgcn_mfma_f32_16x16x32_bf16(au,  bu,  su[nt], 0, 0, 0);
            sv[nt] = __builtin_amdgcn_mfma_f32_16x16x32_bf16(aeh, beh, sv[nt], 0, 0, 0);
            kv[nt] = __builtin_amdgcn_mfma_f32_16x16x32_bf16(aeh, bv,  kv[nt], 0, 0, 0);
            kv[nt] = __builtin_amdgcn_mfma_f32_16x16x32_bf16(ael, bv,  kv[nt], 0, 0, 0);
        }
    }
    float* dst = part + (size_t)(split * 16 + p) * 3 * 4096;
#pragma unroll
    for (int nt = 0; nt < 4; nt++)
#pragma unroll
        for (int reg = 0; reg < 4; reg++) {
            int off = (w * 16 + quad * 4 + reg) * 64 + nt * 16 + lm;
            dst[off] = su[nt][reg];
            dst[4096 + off] = sv[nt][reg];
            dst[8192 + off] = kv[nt][reg];
        }
}

// ================= agf_out + ortho (merges gram partials, scales) =================
__global__ __launch_bounds__(256) void agf_ortho(const float* __restrict__ U, const float* __restrict__ Sg,
                                                 const float* __restrict__ gam, const float* __restrict__ part,
                                                 const float* __restrict__ Spart, float* __restrict__ out) {
    int p = blockIdx.y;
    int tid = threadIdx.x;
    __shared__ float cis[64];
    __shared__ float red[4][64];
    {
        int d = tid & 63, grp = tid >> 6;
        float s = 0.0f;
#pragma unroll
        for (int i = 0; i < 8; i++) s += Spart[(p * 32 + grp * 8 + i) * 64 + d];
        red[grp][d] = s;
        __syncthreads();
        if (tid < 64) cis[tid] = 1.0f / (red[0][tid] + red[1][tid] + red[2][tid] + red[3][tid]);
        __syncthreads();
    }
    if (blockIdx.x == 32) {
        float s = 0.0f;
        for (int idx = tid; idx < 8192; idx += 256) {
            int g = idx >> 12, i = idx & 4095;
            float v = 0.0f;
#pragma unroll
            for (int sp = 0; sp < 4; sp++) v += part[((size_t)(sp * 16 + p) * 3 + g) * 4096 + i];
            if (g) v *= cis[i >> 6] * cis[i & 63];
            float dg = ((i >> 6) == (i & 63)) ? 1.0f : 0.0f;
            s += fabsf(v - dg);
        }
#pragma unroll
        for (int o = 32; o > 0; o >>= 1) s += __shfl_xor(s, o);
        __shared__ float r4[4];
        if ((tid & 63) == 0) r4[tid >> 6] = s;
        __syncthreads();
        if (tid == 0) atomicAdd(&out[LOSS_BASE + (p >> 2)], (r4[0] + r4[1] + r4[2] + r4[3]) * (1.0f / 16384.0f));
        return;
    }
    int lt = blockIdx.x;
    int b = p >> 2, h = p & 3;
    __shared__ __align__(16) float kvs[64][68];
    __shared__ __align__(16) float ugs[64][68];
    for (int idx = tid; idx < 4096; idx += 256) {
        float v = 0.0f;
#pragma unroll
        for (int sp = 0; sp < 4; sp++) v += part[((size_t)(sp * 16 + p) * 3 + 2) * 4096 + idx];
        kvs[idx >> 6][idx & 63] = v * cis[idx >> 6];
    }
    {
        int row = tid >> 2;
        int c16 = (tid & 3) * 16;
        size_t ibase = ((size_t)((b * SEQ + lt * 64 + row) * NH + h)) * D + c16;
        float uv[16];
        load16(U + ibase, uv);
        float mx = uv[0];
#pragma unroll
        for (int k = 1; k < 16; k++) mx = fmaxf(mx, uv[k]);
        mx = fmaxf(mx, __shfl_xor(mx, 1));
        mx = fmaxf(mx, __shfl_xor(mx, 2));
        float sm = 0.0f;
#pragma unroll
        for (int k = 0; k < 16; k++) { uv[k] = __expf(uv[k] - mx); sm += uv[k]; }
        sm += __shfl_xor(sm, 1);
        sm += __shfl_xor(sm, 2);
        float inv = 1.0f / sm;
        float sg[16];
        load16(Sg + ibase, sg);
        float g0 = gam[0], g1 = gam[1], g2 = gam[2], g3 = gam[3];
#pragma unroll
        for (int k = 0; k < 16; k++) {
            float sig = 1.0f / (1.0f + __expf(-sg[k]));
            float x1 = 2.0f * sig;
            float x2 = 1.875f * sig * x1 - 0.75f;
            float x3 = 1.8666666666666667f * sig * x2 - 0.8f * x1;
            float gf = g0 + g1 * x1 + g2 * x2 + g3 * x3;
            ugs[row][c16 + k] = uv[k] * inv * gf;
        }
    }
    __syncthreads();
    int tx = tid & 15, ty = tid >> 4;
    float acc[4][4] = {};
#pragma unroll 8
    for (int x = 0; x < 64; x++) {
        float4 kt = *(const float4*)&kvs[x][tx * 4];
        float kb[4] = {kt.x, kt.y, kt.z, kt.w};
#pragma unroll
        for (int a = 0; a < 4; a++) {
            float ua = ugs[ty * 4 + a][x];
#pragma unroll
            for (int e2 = 0; e2 < 4; e2++) acc[a][e2] = fmaf(ua, kb[e2], acc[a][e2]);
        }
    }
#pragma unroll
    for (int a = 0; a < 4; a++)
#pragma unroll
        for (int e2 = 0; e2 < 4; e2++)
            out[((size_t)(b * SEQ + lt * 64 + ty * 4 + a) * HOUT + h) * D + tx * 4 + e2] = acc[a][e2];
}

// ================= flash4: transposed MFMA orientation, hi-only K, prefetch =================
#define LSTR 72
#define FIXM 10.0f

__global__ __launch_bounds__(256, 4) void flash4(const unsigned short* __restrict__ usb,
                                                 const float* __restrict__ Q,
                                                 float* __restrict__ Opart, float* __restrict__ lpart) {
    int qt = blockIdx.x, p = blockIdx.y, half = blockIdx.z;
    int b = p >> 2, h = p & 3;
    const unsigned short* Khi  = usb;
    const unsigned short* VbfT = usb + USZ;
    __shared__ __align__(16) unsigned short Kl[64 * LSTR];
    __shared__ __align__(16) unsigned short Vl[64 * LSTR];
    __shared__ __align__(16) unsigned short Ph[4][16 * LSTR];
    const int tid = threadIdx.x;
    const int w = tid >> 6, lane = tid & 63, lm = lane & 15, quad = lane >> 4;
    const int srow = tid >> 2, sseg = (tid & 3) * 16;

    // Q b-frags (n-side): B[n=qrow=lm][k=d=ks*32+quad*8+j], scale 1/8, hi/lo
    bf16x8 qhi[2], qlo[2];
    {
        int row = qt * 64 + w * 16 + lm;
        const float* qp = Q + ((size_t)(b * SEQ + row) * NH + h) * D + quad * 8;
#pragma unroll
        for (int ks = 0; ks < 2; ks++) {
            float4 a0 = *(const float4*)(qp + ks * 32);
            float4 a1 = *(const float4*)(qp + ks * 32 + 4);
            float qq[8] = {a0.x, a0.y, a0.z, a0.w, a1.x, a1.y, a1.z, a1.w};
#pragma unroll
            for (int j = 0; j < 8; j++) {
                float xs = qq[j] * 0.125f;
                unsigned short hi = f2bf(xs);
                qhi[ks][j] = (short)hi;
                qlo[ks][j] = (short)f2bf(xs - bf2f(hi));
            }
        }
    }

    float rsum = 0.0f;
    f32x4 o[4];
#pragma unroll
    for (int t = 0; t < 4; t++) o[t] = (f32x4){0.f, 0.f, 0.f, 0.f};

    // prefetch tile 0
    us8 kr0, kr1, vr0, vr1;
    {
        int kt = half * 16;
        size_t kb = ((size_t)p * SEQ + kt * 64 + srow) * 64 + sseg;
        kr0 = *(const us8*)(Khi + kb); kr1 = *(const us8*)(Khi + kb + 8);
        size_t vb = ((size_t)p * 64 + srow) * 2048 + kt * 64 + sseg;
        vr0 = *(const us8*)(VbfT + vb); vr1 = *(const us8*)(VbfT + vb + 8);
    }

    for (int it = 0; it < 16; ++it) {
        __syncthreads();
        *(us8*)&Kl[srow * LSTR + sseg] = kr0; *(us8*)&Kl[srow * LSTR + sseg + 8] = kr1;
        *(us8*)&Vl[srow * LSTR + sseg] = vr0; *(us8*)&Vl[srow * LSTR + sseg + 8] = vr1;
        if (it < 15) {
            int kn = half * 16 + it + 1;
            size_t kb = ((size_t)p * SEQ + kn * 64 + srow) * 64 + sseg;
            kr0 = *(const us8*)(Khi + kb); kr1 = *(const us8*)(Khi + kb + 8);
            size_t vb = ((size_t)p * 64 + srow) * 2048 + kn * 64 + sseg;
            vr0 = *(const us8*)(VbfT + vb); vr1 = *(const us8*)(VbfT + vb + 8);
        }
        __syncthreads();

        // S^T[m=key][n=qrow] = K·Q^T  (2-pass hi/lo on Q only)
        f32x4 s[4];
#pragma unroll
        for (int t = 0; t < 4; t++) s[t] = (f32x4){0.f, 0.f, 0.f, 0.f};
#pragma unroll
        for (int t = 0; t < 4; t++) {
#pragma unroll
            for (int ks = 0; ks < 2; ks++) {
                bf16x8 a = *(const bf16x8*)&Kl[(t * 16 + lm) * LSTR + ks * 32 + quad * 8];
                s[t] = __builtin_amdgcn_mfma_f32_16x16x32_bf16(a, qhi[ks], s[t], 0, 0, 0);
                s[t] = __builtin_amdgcn_mfma_f32_16x16x32_bf16(a, qlo[ks], s[t], 0, 0, 0);
            }
        }

        // exp(s - FIXM), pack 4 bf16, write b64 to Ph[qrow=lm][key]; scalar rsum
#pragma unroll
        for (int t = 0; t < 4; t++) {
            float e0 = __expf(s[t][0] - FIXM);
            float e1 = __expf(s[t][1] - FIXM);
            float e2 = __expf(s[t][2] - FIXM);
            float e3 = __expf(s[t][3] - FIXM);
            rsum += (e0 + e1) + (e2 + e3);
            union { __hip_bfloat162 h2[2]; us4 u4; } pk;
            pk.h2[0] = __float22bfloat162_rn(make_float2(e0, e1));
            pk.h2[1] = __float22bfloat162_rn(make_float2(e2, e3));
            *(us4*)&Ph[w][lm * LSTR + t * 16 + quad * 4] = pk.u4;
        }
        // same-wave LDS ordering via lgkmcnt

        bf16x8 pb0 = *(const bf16x8*)&Ph[w][lm * LSTR + quad * 8];
        bf16x8 pb1 = *(const bf16x8*)&Ph[w][lm * LSTR + 32 + quad * 8];
        // O^T[m=d][n=qrow] += V^T·P^T
#pragma unroll
        for (int dt = 0; dt < 4; dt++) {
            bf16x8 a0 = *(const bf16x8*)&Vl[(dt * 16 + lm) * LSTR + quad * 8];
            o[dt] = __builtin_amdgcn_mfma_f32_16x16x32_bf16(a0, pb0, o[dt], 0, 0, 0);
            bf16x8 a1 = *(const bf16x8*)&Vl[(dt * 16 + lm) * LSTR + 32 + quad * 8];
            o[dt] = __builtin_amdgcn_mfma_f32_16x16x32_bf16(a1, pb1, o[dt], 0, 0, 0);
        }
    }

    // epilogue: lane's column is qrow=lm; vectorized partial stores
    rsum += __shfl_xor(rsum, 16);
    rsum += __shfl_xor(rsum, 32);
    int row = qt * 64 + w * 16 + lm;
    size_t ob = ((size_t)(half * 16 + p) * SEQ + row) * 64;
#pragma unroll
    for (int dt = 0; dt < 4; dt++)
        *(f32x4*)(Opart + ob + dt * 16 + quad * 4) = o[dt];
    if (quad == 0) lpart[(size_t)(half * 16 + p) * SEQ + row] = rsum;
}

// ================= merge split-K halves =================
__global__ __launch_bounds__(256) void smerge(const float* __restrict__ Opart, const float* __restrict__ lpart,
                                              float* __restrict__ out) {
    int idx = blockIdx.x * 256 + threadIdx.x;   // [p][l][16 dq]
    int p = idx >> 15;
    int rem = idx & 32767;
    int l = rem >> 4, dq = rem & 15;
    int b = p >> 2, h = p & 3;
    size_t o0 = ((size_t)p * SEQ + l) * 64 + dq * 4;
    size_t o1 = ((size_t)(16 + p) * SEQ + l) * 64 + dq * 4;
    f32x4 a = *(const f32x4*)(Opart + o0);
    f32x4 c = *(const f32x4*)(Opart + o1);
    float inv = 1.0f / (lpart[(size_t)p * SEQ + l] + lpart[(size_t)(16 + p) * SEQ + l]);
    *(f32x4*)(out + ((size_t)(b * SEQ + l) * HOUT + 4 + h) * D + dq * 4) = (a + c) * inv;
}

extern "C" void kernel_launch(void* const* d_in, const int* in_sizes, int n_in,
                              void* d_out, int out_size, void* d_ws, size_t ws_size,
                              hipStream_t stream) {
    (void)in_sizes; (void)n_in; (void)out_size; (void)ws_size;
    const float* U    = (const float*)d_in[0];
    const float* Sg   = (const float*)d_in[1];
    const float* V    = (const float*)d_in[2];
    const float* vals = (const float*)d_in[3];
    const float* Qs   = (const float*)d_in[4];
    const float* Ks   = (const float*)d_in[5];
    const float* Vv   = (const float*)d_in[6];
    const float* gam  = (const float*)d_in[7];
    float* out = (float*)d_out;

    float* ws = (float*)d_ws;
    float* part  = ws + OFF_PART;
    float* Spart = ws + OFF_SPART;
    float* lpart = ws + OFF_LPART;
    float* Opart = ws + OFF_OPART;
    unsigned short* usb = (unsigned short*)(ws + OFF_US);

    prep<<<dim3(32, 16), 256, 0, stream>>>(U, V, vals, Ks, Vv, ws, usb, out);
    gram<<<dim3(4, 16), 256, 0, stream>>>(usb, part);
    agf_ortho<<<dim3(33, 16), 256, 0, stream>>>(U, Sg, gam, part, Spart, out);
    flash4<<<dim3(32, 16, 2), 256, 0, stream>>>(usb, Qs, Opart, lpart);
    smerge<<<(NPAIR * SEQ * 16) / 256, 256, 0, stream>>>(Opart, lpart, out);
}